// Round 9
// baseline (3642.907 us; speedup 1.0000x reference)
//
#include <hip/hip_runtime.h>
#include <math.h>

#define NR 8192      // NA == NT
#define DIM 256
#define NBLK 512     // fused-kernel blocks == column-partial chunks (2 per CU)
#define CROWS 16     // rows per chunk
#define RSC 2        // rows per sub-chunk
#define NSUB 8       // sub-chunks per chunk
// 10 * log2(e): converts distances directly into base-2 log domain
#define SCALE2 14.426950408889634f

typedef unsigned short ushort_t;
typedef __attribute__((ext_vector_type(8))) short bfrag;   // 8 bf16 (4 VGPRs)
typedef __attribute__((ext_vector_type(4))) float facc;    // 4 fp32 acc

// v_exp_f32 / v_log_f32 are base-2 natively — use them raw
__device__ __forceinline__ float fexp2(float x) {
#if __has_builtin(__builtin_amdgcn_exp2f)
    return __builtin_amdgcn_exp2f(x);
#else
    return exp2f(x);
#endif
}
__device__ __forceinline__ float flog2(float x) {
#if __has_builtin(__builtin_amdgcn_logf)
    return __builtin_amdgcn_logf(x);
#else
    return log2f(x);
#endif
}

// async global->LDS copy, 16 B per lane, no transit VGPRs.
__device__ __forceinline__ void gl2lds16(const float* gp, float* lp) {
#if __has_builtin(__builtin_amdgcn_global_load_lds)
    __builtin_amdgcn_global_load_lds(
        (const __attribute__((address_space(1))) unsigned int*)gp,
        (__attribute__((address_space(3))) unsigned int*)lp, 16, 0, 0);
#else
    *(float4*)lp = *(const float4*)gp;   // fallback: callers pass lane-adjusted ptrs
#endif
}

// raw waits/barrier: barrier WITHOUT vmcnt(0) drain; explicit vmcnt gate.
__device__ __forceinline__ void wait_vm0()  { asm volatile("s_waitcnt vmcnt(0)" ::: "memory"); }
__device__ __forceinline__ void bar_lgkm()  { asm volatile("s_waitcnt lgkmcnt(0)\ns_barrier" ::: "memory"); }

// base-2 online LSE combine
__device__ __forceinline__ void lse_comb2(float& m, float& s, float mo, float so) {
    float nm = fmaxf(m, mo);
    s = s * fexp2(m - nm) + so * fexp2(mo - nm);
    m = nm;
}

// grouped-4 online LSE update (1 tree-max + 1 correction exp per 4 values)
__device__ __forceinline__ void lse_upd4(float& m, float& s,
                                         float v0, float v1, float v2, float v3) {
    float m4 = fmaxf(fmaxf(v0, v1), fmaxf(v2, v3));
    float nm = fmaxf(m, m4);
    float e = fexp2(v0 - nm) + fexp2(v1 - nm) + fexp2(v2 - nm) + fexp2(v3 - nm);
    s = fmaf(s, fexp2(m - nm), e);
    m = nm;
}

// grouped-2 online LSE update
__device__ __forceinline__ void lse_upd2(float& m, float& s, float v0, float v1) {
    float m2 = fmaxf(v0, v1);
    float nm = fmaxf(m, m2);
    float e = fexp2(v0 - nm) + fexp2(v1 - nm);
    s = fmaf(s, fexp2(m - nm), e);
    m = nm;
}

// RNE float -> bf16 bits (manual: deterministic, no API variance)
__device__ __forceinline__ ushort_t f2bf(float x) {
    unsigned u = __float_as_uint(x);
    u += 0x7FFFu + ((u >> 16) & 1u);
    return (ushort_t)(u >> 16);
}
__device__ __forceinline__ float bf2f(ushort_t b) {
    return __uint_as_float(((unsigned)b) << 16);
}

// ---------------- init ----------------
__global__ void init_zero(float* __restrict__ g) {
    int t = blockIdx.x * 256 + threadIdx.x;
    if (t < NR) g[t] = 0.0f;
}

// ---------------- out[M,DIM] = A[M,DIM] @ W[DIM,DIM] + bias (2 problems, z-dim) ----
__global__ __launch_bounds__(256) void gemm_qk2(const float* __restrict__ A0,
                                                const float* __restrict__ W0,
                                                const float* __restrict__ bias0,
                                                float* __restrict__ out0,
                                                const float* __restrict__ A1,
                                                const float* __restrict__ W1,
                                                const float* __restrict__ bias1,
                                                float* __restrict__ out1) {
    const float* A    = blockIdx.z ? A1 : A0;
    const float* W    = blockIdx.z ? W1 : W0;
    const float* bias = blockIdx.z ? bias1 : bias0;
    float* out        = blockIdx.z ? out1 : out0;
    __shared__ float As[16][68];
    __shared__ float Ws[16][68];
    const int t  = threadIdx.x;
    const int r0 = blockIdx.x * 64;
    const int c0 = blockIdx.y * 64;
    const int ty = t >> 4, tx = t & 15;
    const int arow = t >> 2;
    const int ak   = (t & 3) * 4;
    const int wrow = t >> 4;
    const int wcol = (t & 15) * 4;
    float acc[4][4] = {};
    for (int k0 = 0; k0 < DIM; k0 += 16) {
        float4 av = *(const float4*)(A + (size_t)(r0 + arow) * DIM + k0 + ak);
        float4 wv = *(const float4*)(W + (size_t)(k0 + wrow) * DIM + c0 + wcol);
        __syncthreads();
        As[ak + 0][arow] = av.x; As[ak + 1][arow] = av.y;
        As[ak + 2][arow] = av.z; As[ak + 3][arow] = av.w;
        *(float4*)&Ws[wrow][wcol] = wv;
        __syncthreads();
#pragma unroll
        for (int kk = 0; kk < 16; ++kk) {
            float4 a = *(const float4*)&As[kk][ty * 4];
            float4 b = *(const float4*)&Ws[kk][tx * 4];
            float aa[4] = {a.x, a.y, a.z, a.w};
            float bb[4] = {b.x, b.y, b.z, b.w};
#pragma unroll
            for (int i = 0; i < 4; ++i)
#pragma unroll
                for (int j = 0; j < 4; ++j)
                    acc[i][j] = fmaf(aa[i], bb[j], acc[i][j]);
        }
    }
#pragma unroll
    for (int i = 0; i < 4; ++i) {
        float4 o;
        o.x = acc[i][0] + bias[c0 + tx * 4 + 0];
        o.y = acc[i][1] + bias[c0 + tx * 4 + 1];
        o.z = acc[i][2] + bias[c0 + tx * 4 + 2];
        o.w = acc[i][3] + bias[c0 + tx * 4 + 3];
        *(float4*)(out + (size_t)(r0 + ty * 4 + i) * DIM + c0 + tx * 4) = o;
    }
}

// ---------------- row squared norms (q and k in one launch) ----------------
__global__ __launch_bounds__(64) void row_norm2(const float* __restrict__ q,
                                                float* __restrict__ qn,
                                                const float* __restrict__ k,
                                                float* __restrict__ kn) {
    const int sel = blockIdx.x >> 13;          // 0: q, 1: k (8192 blocks each)
    const int row = blockIdx.x & (NR - 1);
    const int lane = threadIdx.x;
    const float* x = sel ? k : q;
    float* out     = sel ? kn : qn;
    float4 v = *(const float4*)(x + (size_t)row * DIM + lane * 4);
    float s = v.x * v.x + v.y * v.y + v.z * v.z + v.w * v.w;
#pragma unroll
    for (int off = 32; off > 0; off >>= 1) s += __shfl_xor(s, off);
    if (lane == 0) out[row] = s;
}

// ---------------- split fp32 -> bf16 hi + lo, q and k in one launch --------------
__global__ __launch_bounds__(256) void split_bf16_2(const float* __restrict__ q,
                                                    ushort_t* __restrict__ qh,
                                                    ushort_t* __restrict__ ql,
                                                    const float* __restrict__ k,
                                                    ushort_t* __restrict__ kh,
                                                    ushort_t* __restrict__ kl) {
    const int sel = blockIdx.x >> 11;          // 2048 blocks per problem
    const int b = blockIdx.x & 2047;
    const float* x = sel ? k : q;
    ushort_t* hi   = sel ? kh : qh;
    ushort_t* lo   = sel ? kl : ql;
    const int idx = (b * 256 + threadIdx.x) * 4;
    float4 v = *(const float4*)(x + idx);
    ushort_t h0 = f2bf(v.x), h1 = f2bf(v.y), h2 = f2bf(v.z), h3 = f2bf(v.w);
    ushort4 hv = make_ushort4(h0, h1, h2, h3);
    ushort4 lv = make_ushort4(f2bf(v.x - bf2f(h0)), f2bf(v.y - bf2f(h1)),
                              f2bf(v.z - bf2f(h2)), f2bf(v.w - bf2f(h3)));
    *(ushort4*)(hi + idx) = hv;
    *(ushort4*)(lo + idx) = lv;
}

// ---------------- S = SCALE2*(qn_i + kn_j - 2*q_i.k_j) via split-bf16 MFMA ----------
// R9: (a) k0 loop fully unrolled — the un-unrolled loop serialized 16 L2 loads
// against 64 MFMAs per step (MfmaUtil 21%); full unroll lets the scheduler
// software-pipeline within its own register budget. (b) bijective XCD swizzle
// (4096 % 8 == 0): each XCD gets 8 contiguous tile-rows -> A-panels (1 MB)
// become L2-resident per XCD.
__global__ __launch_bounds__(256) void dist_mfma(const ushort_t* __restrict__ qh,
                                                 const ushort_t* __restrict__ ql,
                                                 const ushort_t* __restrict__ kh,
                                                 const ushort_t* __restrict__ kl,
                                                 const float* __restrict__ qn,
                                                 const float* __restrict__ kn,
                                                 float* __restrict__ S) {
    const int t = threadIdx.x;
    const int wv = t >> 6, lane = t & 63;
    // XCD-aware remap of the flattened 4096-block grid (bijective: 4096%8==0)
    const int lid = blockIdx.y * 64 + blockIdx.x;
    const int swz = (lid & 7) * 512 + (lid >> 3);
    const int bx = swz & 63, by = swz >> 6;
    const int r0 = by * 128 + (wv >> 1) * 64;
    const int c0 = bx * 128 + (wv & 1) * 64;
    const int fr = lane & 15;       // row (A) / col (B) within 16x16 tile
    const int fq = lane >> 4;       // quad -> k-subrange / C-row group
    facc acc[4][4];
#pragma unroll
    for (int i = 0; i < 4; ++i)
#pragma unroll
        for (int j = 0; j < 4; ++j) acc[i][j] = (facc){0.f, 0.f, 0.f, 0.f};

#pragma unroll
    for (int k0 = 0; k0 < DIM; k0 += 32) {
        const int ks = k0 + fq * 8;
        bfrag ah[4], al[4], bh[4], bl[4];
#pragma unroll
        for (int mi = 0; mi < 4; ++mi) {
            const size_t ao = (size_t)(r0 + mi * 16 + fr) * DIM + ks;
            ah[mi] = *(const bfrag*)(qh + ao);
            al[mi] = *(const bfrag*)(ql + ao);
        }
#pragma unroll
        for (int ni = 0; ni < 4; ++ni) {
            const size_t bo = (size_t)(c0 + ni * 16 + fr) * DIM + ks;
            bh[ni] = *(const bfrag*)(kh + bo);
            bl[ni] = *(const bfrag*)(kl + bo);
        }
#pragma unroll
        for (int mi = 0; mi < 4; ++mi)
#pragma unroll
            for (int ni = 0; ni < 4; ++ni) {
                acc[mi][ni] = __builtin_amdgcn_mfma_f32_16x16x32_bf16(ah[mi], bh[ni], acc[mi][ni], 0, 0, 0);
                acc[mi][ni] = __builtin_amdgcn_mfma_f32_16x16x32_bf16(ah[mi], bl[ni], acc[mi][ni], 0, 0, 0);
                acc[mi][ni] = __builtin_amdgcn_mfma_f32_16x16x32_bf16(al[mi], bh[ni], acc[mi][ni], 0, 0, 0);
                acc[mi][ni] = __builtin_amdgcn_mfma_f32_16x16x32_bf16(al[mi], bl[ni], acc[mi][ni], 0, 0, 0);
            }
    }
    // epilogue: S[row][col] = (qn + kn - 2*dot) * SCALE2
#pragma unroll
    for (int mi = 0; mi < 4; ++mi) {
        float qnr[4];
#pragma unroll
        for (int r = 0; r < 4; ++r) qnr[r] = qn[r0 + mi * 16 + fq * 4 + r];
#pragma unroll
        for (int ni = 0; ni < 4; ++ni) {
            const int col = c0 + ni * 16 + fr;
            const float knc = kn[col];
#pragma unroll
            for (int r = 0; r < 4; ++r) {
                const int row = r0 + mi * 16 + fq * 4 + r;
                S[(size_t)row * NR + col] = (qnr[r] + knc - 2.0f * acc[mi][ni][r]) * SCALE2;
            }
        }
    }
}

// ---------------- MLP logits: relu(A@W1+b1)@W2 + b2 ----------------
__global__ __launch_bounds__(128) void mlp_logits(const float* __restrict__ A,
                                                  const float* __restrict__ W1,
                                                  const float* __restrict__ b1,
                                                  const float* __restrict__ W2,
                                                  const float* __restrict__ b2,
                                                  float* __restrict__ logits) {
    __shared__ float ar[DIM];
    __shared__ float red[2];
    const int t = threadIdx.x;
    const int row = blockIdx.x;
    *(float2*)&ar[t * 2] = *(const float2*)(A + (size_t)row * DIM + t * 2);
    __syncthreads();
    float h = b1[t];
#pragma unroll 8
    for (int kk = 0; kk < DIM; ++kk) h = fmaf(ar[kk], W1[kk * 128 + t], h);
    float val = fmaxf(h, 0.0f) * W2[t];
#pragma unroll
    for (int off = 32; off > 0; off >>= 1) val += __shfl_xor(val, off);
    if ((t & 63) == 0) red[t >> 6] = val;
    __syncthreads();
    if (t == 0) logits[row] = red[0] + red[1] + b2[0];
}

// ---------------- softmax over 8192 logits -> log2(b + 1e-20) ----------------
__global__ __launch_bounds__(1024) void softmax_logb(const float* __restrict__ logits,
                                                     float* __restrict__ logb2) {
    __shared__ float redm[16], reds[16];
    const int t = threadIdx.x;
    float l[8];
    float m = -INFINITY;
#pragma unroll
    for (int i = 0; i < 8; ++i) { l[i] = logits[i * 1024 + t]; m = fmaxf(m, l[i]); }
#pragma unroll
    for (int off = 32; off > 0; off >>= 1) m = fmaxf(m, __shfl_xor(m, off));
    if ((t & 63) == 0) redm[t >> 6] = m;
    __syncthreads();
    if (t < 64) {
        float v = (t < 16) ? redm[t] : -INFINITY;
#pragma unroll
        for (int off = 8; off > 0; off >>= 1) v = fmaxf(v, __shfl_xor(v, off));
        if (t == 0) redm[0] = v;
    }
    __syncthreads();
    m = redm[0];
    float s = 0.0f;
#pragma unroll
    for (int i = 0; i < 8; ++i) s += __expf(l[i] - m);
#pragma unroll
    for (int off = 32; off > 0; off >>= 1) s += __shfl_xor(s, off);
    if ((t & 63) == 0) reds[t >> 6] = s;
    __syncthreads();
    if (t < 64) {
        float v = (t < 16) ? reds[t] : 0.0f;
#pragma unroll
        for (int off = 8; off > 0; off >>= 1) v += __shfl_xor(v, off);
        if (t == 0) reds[0] = v;
    }
    __syncthreads();
    s = reds[0];
    float invs = 1.0f / s;
#pragma unroll
    for (int i = 0; i < 8; ++i)
        logb2[i * 1024 + t] = log2f(__expf(l[i] - m) * invs + 1e-20f);
}

// ---------------- fused iteration: DMA staging + 2 blocks/CU overlap ----------------
// (R0-proven structure: 54 us/iter, VGPR=64, zero scratch.)
__global__ __launch_bounds__(512, 4) void iter_fused(const float* __restrict__ S,
                                                     const float* __restrict__ g,
                                                     const float* __restrict__ logb2,
                                                     float* __restrict__ f,
                                                     float* __restrict__ pm) {
    __shared__ float buf[RSC][NR];      // 64 KB staging (single buffer)
    __shared__ float redm[8], reds[8];
    const int t = threadIdx.x;
    const int wv = t >> 6, lane = t & 63;
    const int chunk = blockIdx.x;
    const int r0 = chunk * CROWS;
    const int rw = wv >> 2;             // row (0..1) within sub-chunk
    const int qt = wv & 3;              // quarter of the row this wave handles
    const int qbase = qt * 2048;
    const int loff = lane * 4;

    // preload this wave's g quarter (constant within one launch): 8 float4
    float4 greg[8];
#pragma unroll
    for (int it = 0; it < 8; ++it)
        greg[it] = *(const float4*)(g + qbase + it * 256 + loff);

    // column accumulators: thread t owns cols {j*2048 + t*4 + c}
    float cm[4][4], cs[4][4];
#pragma unroll
    for (int j = 0; j < 4; ++j)
#pragma unroll
        for (int c = 0; c < 4; ++c) { cm[j][c] = -INFINITY; cs[j][c] = 0.0f; }

    // prologue: DMA sub-chunk 0
    {
        const float* Sr = S + (size_t)(r0 + rw) * NR + qbase;
        float* ld = &buf[rw][qbase];
#pragma unroll
        for (int it = 0; it < 8; ++it)
#if __has_builtin(__builtin_amdgcn_global_load_lds)
            gl2lds16(Sr + it * 256 + loff, ld + it * 256);
#else
            gl2lds16(Sr + it * 256 + loff, ld + it * 256 + loff);
#endif
    }

    for (int sc = 0; sc < NSUB; ++sc) {
        wait_vm0();   // own DMA(sc) (and greg/f stragglers) complete
        // ---- phase 1: row-LSE over this wave's quarter (LDS + g regs) ----
        float m = -INFINITY, s = 0.0f;
#pragma unroll
        for (int it = 0; it < 8; ++it) {
            float4 v = *(const float4*)&buf[rw][qbase + it * 256 + loff];
            float4 gv = greg[it];
            lse_upd4(m, s, v.x + gv.x, v.y + gv.y, v.z + gv.z, v.w + gv.w);
        }
#pragma unroll
        for (int off = 32; off > 0; off >>= 1) {
            float mo = __shfl_xor(m, off);
            float so = __shfl_xor(s, off);
            lse_comb2(m, s, mo, so);
        }
        if (lane == 0) { redm[wv] = m; reds[wv] = s; }
        bar_lgkm();   // barrier A: all DMA(sc) complete block-wide; red visible

        // ---- all threads: combine 4 quarter partials per row -> f0, f1 ----
        float fr[RSC];
#pragma unroll
        for (int r = 0; r < RSC; ++r) {
            float mm = redm[r * 4 + 0], ss = reds[r * 4 + 0];
            lse_comb2(mm, ss, redm[r * 4 + 1], reds[r * 4 + 1]);
            lse_comb2(mm, ss, redm[r * 4 + 2], reds[r * 4 + 2]);
            lse_comb2(mm, ss, redm[r * 4 + 3], reds[r * 4 + 3]);
            fr[r] = logb2[r0 + sc * RSC + r] - (mm + flog2(ss));
        }
        if (t < RSC) f[r0 + sc * RSC + t] = fr[t];

        // ---- phase 2: column partial-LSE over the 2 staged rows (LDS) ----
#pragma unroll
        for (int j = 0; j < 4; ++j) {
            const int c = j * 2048 + t * 4;
            float4 a = *(const float4*)&buf[0][c];
            float4 bb = *(const float4*)&buf[1][c];
            lse_upd2(cm[j][0], cs[j][0], a.x + fr[0], bb.x + fr[1]);
            lse_upd2(cm[j][1], cs[j][1], a.y + fr[0], bb.y + fr[1]);
            lse_upd2(cm[j][2], cs[j][2], a.z + fr[0], bb.z + fr[1]);
            lse_upd2(cm[j][3], cs[j][3], a.w + fr[0], bb.w + fr[1]);
        }
        bar_lgkm();   // barrier B: every wave done reading buf

        // ---- issue DMA for sub-chunk sc+1 (safe: all reads of buf finished) ----
        if (sc + 1 < NSUB) {
            const float* Sn = S + (size_t)(r0 + (sc + 1) * RSC + rw) * NR + qbase;
            float* ld = &buf[rw][qbase];
#pragma unroll
            for (int it = 0; it < 8; ++it)
#if __has_builtin(__builtin_amdgcn_global_load_lds)
                gl2lds16(Sn + it * 256 + loff, ld + it * 256);
#else
                gl2lds16(Sn + it * 256 + loff, ld + it * 256 + loff);
#endif
        }
    }
    // write column partials for this chunk as a single float L = m + log2(s)
#pragma unroll
    for (int j = 0; j < 4; ++j) {
        float4 L;
        L.x = cm[j][0] + flog2(cs[j][0]);
        L.y = cm[j][1] + flog2(cs[j][1]);
        L.z = cm[j][2] + flog2(cs[j][2]);
        L.w = cm[j][3] + flog2(cs[j][3]);
        *(float4*)&pm[(size_t)chunk * NR + j * 2048 + t * 4] = L;
    }
}

// ---------------- combine partials -> g (512 blocks, vectorized, MLP-rich) --------
// R9 rewrite: old version was latency-bound (64 scalar stride-32KB loads/thread,
// 4 waves/CU, ~6 us for 16 MB). New: 512 blocks x 256 threads; block owns 16
// cols; thread (q=t&3, gp=t>>2) loads 8 INDEPENDENT float4s (cols q*4..q*4+3,
// chunks gp*8..gp*8+7), LSE over 8 in regs, xor-shuffle combine over the 16
// gps in its wave, LDS stage [4 waves][4 q], final combine by threads 0..3.
__global__ __launch_bounds__(256) void col_combine(const float* __restrict__ pm,
                                                   float* __restrict__ g,
                                                   float log_a2) {
    __shared__ float4 Lm[4][4], Ls[4][4];   // [wave][q]
    const int t = threadIdx.x;
    const int q = t & 3;
    const int gp = t >> 2;                  // 0..63 chunk-groups (8 chunks each)
    const int w = t >> 6;
    const int c0 = blockIdx.x * 16 + q * 4;
    float4 v[8];
#pragma unroll
    for (int i = 0; i < 8; ++i)
        v[i] = *(const float4*)&pm[(size_t)(gp * 8 + i) * NR + c0];
    // LSE over the 8 chunk values per column component
    float4 m, s;
    m.x = fmaxf(fmaxf(fmaxf(v[0].x, v[1].x), fmaxf(v[2].x, v[3].x)),
                fmaxf(fmaxf(v[4].x, v[5].x), fmaxf(v[6].x, v[7].x)));
    m.y = fmaxf(fmaxf(fmaxf(v[0].y, v[1].y), fmaxf(v[2].y, v[3].y)),
                fmaxf(fmaxf(v[4].y, v[5].y), fmaxf(v[6].y, v[7].y)));
    m.z = fmaxf(fmaxf(fmaxf(v[0].z, v[1].z), fmaxf(v[2].z, v[3].z)),
                fmaxf(fmaxf(v[4].z, v[5].z), fmaxf(v[6].z, v[7].z)));
    m.w = fmaxf(fmaxf(fmaxf(v[0].w, v[1].w), fmaxf(v[2].w, v[3].w)),
                fmaxf(fmaxf(v[4].w, v[5].w), fmaxf(v[6].w, v[7].w)));
    s = make_float4(0.f, 0.f, 0.f, 0.f);
#pragma unroll
    for (int i = 0; i < 8; ++i) {
        s.x += fexp2(v[i].x - m.x);
        s.y += fexp2(v[i].y - m.y);
        s.z += fexp2(v[i].z - m.z);
        s.w += fexp2(v[i].w - m.w);
    }
    // xor-shuffle combine across the wave's 16 gps (same q every 4 lanes)
#pragma unroll
    for (int off = 32; off >= 4; off >>= 1) {
        float mx = __shfl_xor(m.x, off), sx = __shfl_xor(s.x, off);
        lse_comb2(m.x, s.x, mx, sx);
        float my = __shfl_xor(m.y, off), sy = __shfl_xor(s.y, off);
        lse_comb2(m.y, s.y, my, sy);
        float mz = __shfl_xor(m.z, off), sz = __shfl_xor(s.z, off);
        lse_comb2(m.z, s.z, mz, sz);
        float mw = __shfl_xor(m.w, off), sw = __shfl_xor(s.w, off);
        lse_comb2(m.w, s.w, mw, sw);
    }
    if ((t & 63) < 4) { Lm[w][q] = m; Ls[w][q] = s; }   // lane<4 has q==lane
    __syncthreads();
    if (t < 4) {
        float4 M = Lm[0][t], P = Ls[0][t];
#pragma unroll
        for (int ww = 1; ww < 4; ++ww) {
            float4 Mo = Lm[ww][t], Po = Ls[ww][t];
            lse_comb2(M.x, P.x, Mo.x, Po.x);
            lse_comb2(M.y, P.y, Mo.y, Po.y);
            lse_comb2(M.z, P.z, Mo.z, Po.z);
            lse_comb2(M.w, P.w, Mo.w, Po.w);
        }
        float4 o;
        o.x = log_a2 - (M.x + flog2(P.x));
        o.y = log_a2 - (M.y + flog2(P.y));
        o.z = log_a2 - (M.z + flog2(P.z));
        o.w = log_a2 - (M.w + flog2(P.w));
        *(float4*)&g[blockIdx.x * 16 + t * 4] = o;
    }
}

// ---------------- T = exp2(f + S + g), in place; global sum == 1 analytically ------
// note: no __restrict__ on S/out — they alias (in-place)
__global__ __launch_bounds__(256) void write_pass(const float* S,
                                                  const float* __restrict__ f,
                                                  const float* __restrict__ g,
                                                  float* out) {
    const int wv = threadIdx.x >> 6, lane = threadIdx.x & 63;
    const int row = blockIdx.x * 4 + wv;
    const float fi = f[row];
    const float4* Sr = (const float4*)(S + (size_t)row * NR);
    const float4* gr = (const float4*)g;
    float4* Or = (float4*)(out + (size_t)row * NR);
#pragma unroll 4
    for (int it = 0; it < NR / 256; ++it) {
        const int idx = it * 64 + lane;
        float4 sv = Sr[idx];
        float4 gv = gr[idx];
        float4 o;
        o.x = fexp2(fi + sv.x + gv.x);
        o.y = fexp2(fi + sv.y + gv.y);
        o.z = fexp2(fi + sv.z + gv.z);
        o.w = fexp2(fi + sv.w + gv.w);
        Or[idx] = o;
    }
}

extern "C" void kernel_launch(void* const* d_in, const int* in_sizes, int n_in,
                              void* d_out, int out_size, void* d_ws, size_t ws_size,
                              hipStream_t stream) {
    (void)in_sizes; (void)n_in; (void)out_size; (void)ws_size;
    const float* A  = (const float*)d_in[0];
    const float* Tk = (const float*)d_in[1];
    const float* Wq = (const float*)d_in[2];
    const float* bq = (const float*)d_in[3];
    const float* Wk = (const float*)d_in[4];
    const float* bk = (const float*)d_in[5];
    const float* W1 = (const float*)d_in[6];
    const float* b1 = (const float*)d_in[7];
    const float* W2 = (const float*)d_in[8];
    const float* b2 = (const float*)d_in[9];
    float* S  = (float*)d_out;           // 8192x8192 base-2 log_K lives in d_out
    float* ws = (float*)d_ws;
    float* qn     = ws; ws += NR;
    float* kn     = ws; ws += NR;
    float* logb2  = ws; ws += NR;
    float* logits = ws; ws += NR;
    float* f      = ws; ws += NR;
    float* g      = ws; ws += NR;
    float* pm     = ws; ws += (size_t)NBLK * NR;   // 16 MB
    float* q      = ws; ws += (size_t)NR * DIM;    // 8 MB
    float* k      = ws; ws += (size_t)NR * DIM;    // 8 MB
    // bf16 split arrays overlay pm (16.78 MB == 4 x NR*DIM ushorts): they are
    // dead once dist_mfma finishes, before the first iter_fused writes pm.
    ushort_t* qh = (ushort_t*)pm;
    ushort_t* ql = qh + (size_t)NR * DIM;
    ushort_t* kh = ql + (size_t)NR * DIM;
    ushort_t* kl = kh + (size_t)NR * DIM;

    const float log_a2 = -13.0f; // log2(1/8192 + 1e-20)

    init_zero<<<32, 256, 0, stream>>>(g);
    gemm_qk2<<<dim3(128, 4, 2), 256, 0, stream>>>(A, Wq, bq, q, Tk, Wk, bk, k);
    row_norm2<<<2 * NR, 64, 0, stream>>>(q, qn, k, kn);
    split_bf16_2<<<2 * (NR * DIM / 1024), 256, 0, stream>>>(q, qh, ql, k, kh, kl);
    mlp_logits<<<NR, 128, 0, stream>>>(A, W1, b1, W2, b2, logits);
    softmax_logb<<<1, 1024, 0, stream>>>(logits, logb2);
    dist_mfma<<<dim3(64, 64), 256, 0, stream>>>(qh, ql, kh, kl, qn, kn, S);
    for (int it = 0; it < 50; ++it) {
        iter_fused<<<NBLK, 512, 0, stream>>>(S, g, logb2, f, pm);
        col_combine<<<NR / 16, 256, 0, stream>>>(pm, g, log_a2);
    }
    write_pass<<<NR / 4, 256, 0, stream>>>(S, f, g, S);
}

// Round 10
// 3456.742 us; speedup vs baseline: 1.0539x; 1.0539x over previous
//
#include <hip/hip_runtime.h>
#include <math.h>

#define NR 8192      // NA == NT
#define DIM 256
#define NBLK 512     // fused-kernel blocks == column-partial chunks (2 per CU)
#define CROWS 16     // rows per chunk
#define RSC 2        // rows per sub-chunk
#define NSUB 8       // sub-chunks per chunk
// 10 * log2(e): converts distances directly into base-2 log domain
#define SCALE2 14.426950408889634f

typedef unsigned short ushort_t;
typedef __attribute__((ext_vector_type(8))) short bfrag;   // 8 bf16 (4 VGPRs)
typedef __attribute__((ext_vector_type(4))) float facc;    // 4 fp32 acc

// v_exp_f32 / v_log_f32 are base-2 natively — use them raw
__device__ __forceinline__ float fexp2(float x) {
#if __has_builtin(__builtin_amdgcn_exp2f)
    return __builtin_amdgcn_exp2f(x);
#else
    return exp2f(x);
#endif
}
__device__ __forceinline__ float flog2(float x) {
#if __has_builtin(__builtin_amdgcn_logf)
    return __builtin_amdgcn_logf(x);
#else
    return log2f(x);
#endif
}

// async global->LDS copy, 16 B per lane, no transit VGPRs.
__device__ __forceinline__ void gl2lds16(const float* gp, float* lp) {
#if __has_builtin(__builtin_amdgcn_global_load_lds)
    __builtin_amdgcn_global_load_lds(
        (const __attribute__((address_space(1))) unsigned int*)gp,
        (__attribute__((address_space(3))) unsigned int*)lp, 16, 0, 0);
#else
    *(float4*)lp = *(const float4*)gp;   // fallback: callers pass lane-adjusted ptrs
#endif
}

// raw waits/barrier: barrier WITHOUT vmcnt(0) drain; explicit vmcnt gate.
__device__ __forceinline__ void wait_vm0()  { asm volatile("s_waitcnt vmcnt(0)" ::: "memory"); }
__device__ __forceinline__ void bar_lgkm()  { asm volatile("s_waitcnt lgkmcnt(0)\ns_barrier" ::: "memory"); }

// base-2 online LSE combine
__device__ __forceinline__ void lse_comb2(float& m, float& s, float mo, float so) {
    float nm = fmaxf(m, mo);
    s = s * fexp2(m - nm) + so * fexp2(mo - nm);
    m = nm;
}

// grouped-4 online LSE update (1 tree-max + 1 correction exp per 4 values)
__device__ __forceinline__ void lse_upd4(float& m, float& s,
                                         float v0, float v1, float v2, float v3) {
    float m4 = fmaxf(fmaxf(v0, v1), fmaxf(v2, v3));
    float nm = fmaxf(m, m4);
    float e = fexp2(v0 - nm) + fexp2(v1 - nm) + fexp2(v2 - nm) + fexp2(v3 - nm);
    s = fmaf(s, fexp2(m - nm), e);
    m = nm;
}

// grouped-2 online LSE update
__device__ __forceinline__ void lse_upd2(float& m, float& s, float v0, float v1) {
    float m2 = fmaxf(v0, v1);
    float nm = fmaxf(m, m2);
    float e = fexp2(v0 - nm) + fexp2(v1 - nm);
    s = fmaf(s, fexp2(m - nm), e);
    m = nm;
}

// RNE float -> bf16 bits (manual: deterministic, no API variance)
__device__ __forceinline__ ushort_t f2bf(float x) {
    unsigned u = __float_as_uint(x);
    u += 0x7FFFu + ((u >> 16) & 1u);
    return (ushort_t)(u >> 16);
}
__device__ __forceinline__ float bf2f(ushort_t b) {
    return __uint_as_float(((unsigned)b) << 16);
}

// ---------------- init ----------------
__global__ void init_zero(float* __restrict__ g) {
    int t = blockIdx.x * 256 + threadIdx.x;
    if (t < NR) g[t] = 0.0f;
}

// ---------------- out[M,DIM] = A[M,DIM] @ W[DIM,DIM] + bias (2 problems, z-dim) ----
__global__ __launch_bounds__(256) void gemm_qk2(const float* __restrict__ A0,
                                                const float* __restrict__ W0,
                                                const float* __restrict__ bias0,
                                                float* __restrict__ out0,
                                                const float* __restrict__ A1,
                                                const float* __restrict__ W1,
                                                const float* __restrict__ bias1,
                                                float* __restrict__ out1) {
    const float* A    = blockIdx.z ? A1 : A0;
    const float* W    = blockIdx.z ? W1 : W0;
    const float* bias = blockIdx.z ? bias1 : bias0;
    float* out        = blockIdx.z ? out1 : out0;
    __shared__ float As[16][68];
    __shared__ float Ws[16][68];
    const int t  = threadIdx.x;
    const int r0 = blockIdx.x * 64;
    const int c0 = blockIdx.y * 64;
    const int ty = t >> 4, tx = t & 15;
    const int arow = t >> 2;
    const int ak   = (t & 3) * 4;
    const int wrow = t >> 4;
    const int wcol = (t & 15) * 4;
    float acc[4][4] = {};
    for (int k0 = 0; k0 < DIM; k0 += 16) {
        float4 av = *(const float4*)(A + (size_t)(r0 + arow) * DIM + k0 + ak);
        float4 wv = *(const float4*)(W + (size_t)(k0 + wrow) * DIM + c0 + wcol);
        __syncthreads();
        As[ak + 0][arow] = av.x; As[ak + 1][arow] = av.y;
        As[ak + 2][arow] = av.z; As[ak + 3][arow] = av.w;
        *(float4*)&Ws[wrow][wcol] = wv;
        __syncthreads();
#pragma unroll
        for (int kk = 0; kk < 16; ++kk) {
            float4 a = *(const float4*)&As[kk][ty * 4];
            float4 b = *(const float4*)&Ws[kk][tx * 4];
            float aa[4] = {a.x, a.y, a.z, a.w};
            float bb[4] = {b.x, b.y, b.z, b.w};
#pragma unroll
            for (int i = 0; i < 4; ++i)
#pragma unroll
                for (int j = 0; j < 4; ++j)
                    acc[i][j] = fmaf(aa[i], bb[j], acc[i][j]);
        }
    }
#pragma unroll
    for (int i = 0; i < 4; ++i) {
        float4 o;
        o.x = acc[i][0] + bias[c0 + tx * 4 + 0];
        o.y = acc[i][1] + bias[c0 + tx * 4 + 1];
        o.z = acc[i][2] + bias[c0 + tx * 4 + 2];
        o.w = acc[i][3] + bias[c0 + tx * 4 + 3];
        *(float4*)(out + (size_t)(r0 + ty * 4 + i) * DIM + c0 + tx * 4) = o;
    }
}

// ---------------- row squared norms (q and k in one launch) ----------------
__global__ __launch_bounds__(64) void row_norm2(const float* __restrict__ q,
                                                float* __restrict__ qn,
                                                const float* __restrict__ k,
                                                float* __restrict__ kn) {
    const int sel = blockIdx.x >> 13;          // 0: q, 1: k (8192 blocks each)
    const int row = blockIdx.x & (NR - 1);
    const int lane = threadIdx.x;
    const float* x = sel ? k : q;
    float* out     = sel ? kn : qn;
    float4 v = *(const float4*)(x + (size_t)row * DIM + lane * 4);
    float s = v.x * v.x + v.y * v.y + v.z * v.z + v.w * v.w;
#pragma unroll
    for (int off = 32; off > 0; off >>= 1) s += __shfl_xor(s, off);
    if (lane == 0) out[row] = s;
}

// ---------------- split fp32 -> bf16 hi + lo, q and k in one launch --------------
__global__ __launch_bounds__(256) void split_bf16_2(const float* __restrict__ q,
                                                    ushort_t* __restrict__ qh,
                                                    ushort_t* __restrict__ ql,
                                                    const float* __restrict__ k,
                                                    ushort_t* __restrict__ kh,
                                                    ushort_t* __restrict__ kl) {
    const int sel = blockIdx.x >> 11;          // 2048 blocks per problem
    const int b = blockIdx.x & 2047;
    const float* x = sel ? k : q;
    ushort_t* hi   = sel ? kh : qh;
    ushort_t* lo   = sel ? kl : ql;
    const int idx = (b * 256 + threadIdx.x) * 4;
    float4 v = *(const float4*)(x + idx);
    ushort_t h0 = f2bf(v.x), h1 = f2bf(v.y), h2 = f2bf(v.z), h3 = f2bf(v.w);
    ushort4 hv = make_ushort4(h0, h1, h2, h3);
    ushort4 lv = make_ushort4(f2bf(v.x - bf2f(h0)), f2bf(v.y - bf2f(h1)),
                              f2bf(v.z - bf2f(h2)), f2bf(v.w - bf2f(h3)));
    *(ushort4*)(hi + idx) = hv;
    *(ushort4*)(lo + idx) = lv;
}

// ---------------- S = SCALE2*(qn_i + kn_j - 2*q_i.k_j) via split-bf16 MFMA ----------
// R10: XCD swizzle REVERTED (R9: 4.3x FETCH, zero time benefit — kernel is
// issue-bound, not BW-bound). k0 unroll kept (VALUBusy 17->9, neutral).
// KEY CHANGE: MFMAs reordered PRODUCT-MAJOR. R9's order chained the 4 split
// products into the same acc[mi][ni] back-to-back — a serial dependency of 4
// MFMAs (latency ~3x throughput each) the compiler cannot break. Product-major
// gives 15 independent MFMAs between accumulator reuses -> latency hidden.
__global__ __launch_bounds__(256) void dist_mfma(const ushort_t* __restrict__ qh,
                                                 const ushort_t* __restrict__ ql,
                                                 const ushort_t* __restrict__ kh,
                                                 const ushort_t* __restrict__ kl,
                                                 const float* __restrict__ qn,
                                                 const float* __restrict__ kn,
                                                 float* __restrict__ S) {
    const int t = threadIdx.x;
    const int wv = t >> 6, lane = t & 63;
    const int r0 = blockIdx.y * 128 + (wv >> 1) * 64;
    const int c0 = blockIdx.x * 128 + (wv & 1) * 64;
    const int fr = lane & 15;       // row (A) / col (B) within 16x16 tile
    const int fq = lane >> 4;       // quad -> k-subrange / C-row group
    facc acc[4][4];
#pragma unroll
    for (int i = 0; i < 4; ++i)
#pragma unroll
        for (int j = 0; j < 4; ++j) acc[i][j] = (facc){0.f, 0.f, 0.f, 0.f};

#pragma unroll
    for (int k0 = 0; k0 < DIM; k0 += 32) {
        const int ks = k0 + fq * 8;
        bfrag ah[4], al[4], bh[4], bl[4];
#pragma unroll
        for (int mi = 0; mi < 4; ++mi) {
            const size_t ao = (size_t)(r0 + mi * 16 + fr) * DIM + ks;
            ah[mi] = *(const bfrag*)(qh + ao);
            al[mi] = *(const bfrag*)(ql + ao);
        }
#pragma unroll
        for (int ni = 0; ni < 4; ++ni) {
            const size_t bo = (size_t)(c0 + ni * 16 + fr) * DIM + ks;
            bh[ni] = *(const bfrag*)(kh + bo);
            bl[ni] = *(const bfrag*)(kl + bo);
        }
        // product-major: consecutive MFMAs target different accumulators
#pragma unroll
        for (int mi = 0; mi < 4; ++mi)
#pragma unroll
            for (int ni = 0; ni < 4; ++ni)
                acc[mi][ni] = __builtin_amdgcn_mfma_f32_16x16x32_bf16(ah[mi], bh[ni], acc[mi][ni], 0, 0, 0);
#pragma unroll
        for (int mi = 0; mi < 4; ++mi)
#pragma unroll
            for (int ni = 0; ni < 4; ++ni)
                acc[mi][ni] = __builtin_amdgcn_mfma_f32_16x16x32_bf16(ah[mi], bl[ni], acc[mi][ni], 0, 0, 0);
#pragma unroll
        for (int mi = 0; mi < 4; ++mi)
#pragma unroll
            for (int ni = 0; ni < 4; ++ni)
                acc[mi][ni] = __builtin_amdgcn_mfma_f32_16x16x32_bf16(al[mi], bh[ni], acc[mi][ni], 0, 0, 0);
#pragma unroll
        for (int mi = 0; mi < 4; ++mi)
#pragma unroll
            for (int ni = 0; ni < 4; ++ni)
                acc[mi][ni] = __builtin_amdgcn_mfma_f32_16x16x32_bf16(al[mi], bl[ni], acc[mi][ni], 0, 0, 0);
    }
    // epilogue: S[row][col] = (qn + kn - 2*dot) * SCALE2
#pragma unroll
    for (int mi = 0; mi < 4; ++mi) {
        float qnr[4];
#pragma unroll
        for (int r = 0; r < 4; ++r) qnr[r] = qn[r0 + mi * 16 + fq * 4 + r];
#pragma unroll
        for (int ni = 0; ni < 4; ++ni) {
            const int col = c0 + ni * 16 + fr;
            const float knc = kn[col];
#pragma unroll
            for (int r = 0; r < 4; ++r) {
                const int row = r0 + mi * 16 + fq * 4 + r;
                S[(size_t)row * NR + col] = (qnr[r] + knc - 2.0f * acc[mi][ni][r]) * SCALE2;
            }
        }
    }
}

// ---------------- MLP logits: relu(A@W1+b1)@W2 + b2 ----------------
__global__ __launch_bounds__(128) void mlp_logits(const float* __restrict__ A,
                                                  const float* __restrict__ W1,
                                                  const float* __restrict__ b1,
                                                  const float* __restrict__ W2,
                                                  const float* __restrict__ b2,
                                                  float* __restrict__ logits) {
    __shared__ float ar[DIM];
    __shared__ float red[2];
    const int t = threadIdx.x;
    const int row = blockIdx.x;
    *(float2*)&ar[t * 2] = *(const float2*)(A + (size_t)row * DIM + t * 2);
    __syncthreads();
    float h = b1[t];
#pragma unroll 8
    for (int kk = 0; kk < DIM; ++kk) h = fmaf(ar[kk], W1[kk * 128 + t], h);
    float val = fmaxf(h, 0.0f) * W2[t];
#pragma unroll
    for (int off = 32; off > 0; off >>= 1) val += __shfl_xor(val, off);
    if ((t & 63) == 0) red[t >> 6] = val;
    __syncthreads();
    if (t == 0) logits[row] = red[0] + red[1] + b2[0];
}

// ---------------- softmax over 8192 logits -> log2(b + 1e-20) ----------------
__global__ __launch_bounds__(1024) void softmax_logb(const float* __restrict__ logits,
                                                     float* __restrict__ logb2) {
    __shared__ float redm[16], reds[16];
    const int t = threadIdx.x;
    float l[8];
    float m = -INFINITY;
#pragma unroll
    for (int i = 0; i < 8; ++i) { l[i] = logits[i * 1024 + t]; m = fmaxf(m, l[i]); }
#pragma unroll
    for (int off = 32; off > 0; off >>= 1) m = fmaxf(m, __shfl_xor(m, off));
    if ((t & 63) == 0) redm[t >> 6] = m;
    __syncthreads();
    if (t < 64) {
        float v = (t < 16) ? redm[t] : -INFINITY;
#pragma unroll
        for (int off = 8; off > 0; off >>= 1) v = fmaxf(v, __shfl_xor(v, off));
        if (t == 0) redm[0] = v;
    }
    __syncthreads();
    m = redm[0];
    float s = 0.0f;
#pragma unroll
    for (int i = 0; i < 8; ++i) s += __expf(l[i] - m);
#pragma unroll
    for (int off = 32; off > 0; off >>= 1) s += __shfl_xor(s, off);
    if ((t & 63) == 0) reds[t >> 6] = s;
    __syncthreads();
    if (t < 64) {
        float v = (t < 16) ? reds[t] : 0.0f;
#pragma unroll
        for (int off = 8; off > 0; off >>= 1) v += __shfl_xor(v, off);
        if (t == 0) reds[0] = v;
    }
    __syncthreads();
    s = reds[0];
    float invs = 1.0f / s;
#pragma unroll
    for (int i = 0; i < 8; ++i)
        logb2[i * 1024 + t] = log2f(__expf(l[i] - m) * invs + 1e-20f);
}

// ---------------- fused iteration: DMA staging + 2 blocks/CU overlap ----------------
// (R0-proven structure: 54 us/iter, VGPR=64, zero scratch.)
__global__ __launch_bounds__(512, 4) void iter_fused(const float* __restrict__ S,
                                                     const float* __restrict__ g,
                                                     const float* __restrict__ logb2,
                                                     float* __restrict__ f,
                                                     float* __restrict__ pm) {
    __shared__ float buf[RSC][NR];      // 64 KB staging (single buffer)
    __shared__ float redm[8], reds[8];
    const int t = threadIdx.x;
    const int wv = t >> 6, lane = t & 63;
    const int chunk = blockIdx.x;
    const int r0 = chunk * CROWS;
    const int rw = wv >> 2;             // row (0..1) within sub-chunk
    const int qt = wv & 3;              // quarter of the row this wave handles
    const int qbase = qt * 2048;
    const int loff = lane * 4;

    // preload this wave's g quarter (constant within one launch): 8 float4
    float4 greg[8];
#pragma unroll
    for (int it = 0; it < 8; ++it)
        greg[it] = *(const float4*)(g + qbase + it * 256 + loff);

    // column accumulators: thread t owns cols {j*2048 + t*4 + c}
    float cm[4][4], cs[4][4];
#pragma unroll
    for (int j = 0; j < 4; ++j)
#pragma unroll
        for (int c = 0; c < 4; ++c) { cm[j][c] = -INFINITY; cs[j][c] = 0.0f; }

    // prologue: DMA sub-chunk 0
    {
        const float* Sr = S + (size_t)(r0 + rw) * NR + qbase;
        float* ld = &buf[rw][qbase];
#pragma unroll
        for (int it = 0; it < 8; ++it)
#if __has_builtin(__builtin_amdgcn_global_load_lds)
            gl2lds16(Sr + it * 256 + loff, ld + it * 256);
#else
            gl2lds16(Sr + it * 256 + loff, ld + it * 256 + loff);
#endif
    }

    for (int sc = 0; sc < NSUB; ++sc) {
        wait_vm0();   // own DMA(sc) (and greg/f stragglers) complete
        // ---- phase 1: row-LSE over this wave's quarter (LDS + g regs) ----
        float m = -INFINITY, s = 0.0f;
#pragma unroll
        for (int it = 0; it < 8; ++it) {
            float4 v = *(const float4*)&buf[rw][qbase + it * 256 + loff];
            float4 gv = greg[it];
            lse_upd4(m, s, v.x + gv.x, v.y + gv.y, v.z + gv.z, v.w + gv.w);
        }
#pragma unroll
        for (int off = 32; off > 0; off >>= 1) {
            float mo = __shfl_xor(m, off);
            float so = __shfl_xor(s, off);
            lse_comb2(m, s, mo, so);
        }
        if (lane == 0) { redm[wv] = m; reds[wv] = s; }
        bar_lgkm();   // barrier A: all DMA(sc) complete block-wide; red visible

        // ---- all threads: combine 4 quarter partials per row -> f0, f1 ----
        float fr[RSC];
#pragma unroll
        for (int r = 0; r < RSC; ++r) {
            float mm = redm[r * 4 + 0], ss = reds[r * 4 + 0];
            lse_comb2(mm, ss, redm[r * 4 + 1], reds[r * 4 + 1]);
            lse_comb2(mm, ss, redm[r * 4 + 2], reds[r * 4 + 2]);
            lse_comb2(mm, ss, redm[r * 4 + 3], reds[r * 4 + 3]);
            fr[r] = logb2[r0 + sc * RSC + r] - (mm + flog2(ss));
        }
        if (t < RSC) f[r0 + sc * RSC + t] = fr[t];

        // ---- phase 2: column partial-LSE over the 2 staged rows (LDS) ----
#pragma unroll
        for (int j = 0; j < 4; ++j) {
            const int c = j * 2048 + t * 4;
            float4 a = *(const float4*)&buf[0][c];
            float4 bb = *(const float4*)&buf[1][c];
            lse_upd2(cm[j][0], cs[j][0], a.x + fr[0], bb.x + fr[1]);
            lse_upd2(cm[j][1], cs[j][1], a.y + fr[0], bb.y + fr[1]);
            lse_upd2(cm[j][2], cs[j][2], a.z + fr[0], bb.z + fr[1]);
            lse_upd2(cm[j][3], cs[j][3], a.w + fr[0], bb.w + fr[1]);
        }
        bar_lgkm();   // barrier B: every wave done reading buf

        // ---- issue DMA for sub-chunk sc+1 (safe: all reads of buf finished) ----
        if (sc + 1 < NSUB) {
            const float* Sn = S + (size_t)(r0 + (sc + 1) * RSC + rw) * NR + qbase;
            float* ld = &buf[rw][qbase];
#pragma unroll
            for (int it = 0; it < 8; ++it)
#if __has_builtin(__builtin_amdgcn_global_load_lds)
                gl2lds16(Sn + it * 256 + loff, ld + it * 256);
#else
                gl2lds16(Sn + it * 256 + loff, ld + it * 256 + loff);
#endif
        }
    }
    // write column partials for this chunk as a single float L = m + log2(s)
#pragma unroll
    for (int j = 0; j < 4; ++j) {
        float4 L;
        L.x = cm[j][0] + flog2(cs[j][0]);
        L.y = cm[j][1] + flog2(cs[j][1]);
        L.z = cm[j][2] + flog2(cs[j][2]);
        L.w = cm[j][3] + flog2(cs[j][3]);
        *(float4*)&pm[(size_t)chunk * NR + j * 2048 + t * 4] = L;
    }
}

// ---------------- combine partials -> g (256 blocks, two-level LSE) ----------------
// (R8-proven version restored: coalesced 128B wave loads beat R9's scattered
// 64B "ILP" variant by ~2x.)
__global__ __launch_bounds__(256) void col_combine(const float* __restrict__ pm,
                                                   float* __restrict__ g,
                                                   float log_a2) {
    __shared__ float Lsh[8][32];
    const int cl = threadIdx.x & 31;       // column within block
    const int gp = threadIdx.x >> 5;       // chunk group (0..7), 64 chunks each
    const int col = blockIdx.x * 32 + cl;
    float m = -INFINITY, s = 0.0f;
#pragma unroll
    for (int ch = gp * 64; ch < gp * 64 + 64; ch += 4) {
        float l0 = pm[(size_t)(ch + 0) * NR + col];
        float l1 = pm[(size_t)(ch + 1) * NR + col];
        float l2 = pm[(size_t)(ch + 2) * NR + col];
        float l3 = pm[(size_t)(ch + 3) * NR + col];
        lse_upd4(m, s, l0, l1, l2, l3);
    }
    Lsh[gp][cl] = m + flog2(s);
    __syncthreads();
    if (gp == 0) {
        float mm = -INFINITY, ss = 0.0f;
        lse_upd4(mm, ss, Lsh[0][cl], Lsh[1][cl], Lsh[2][cl], Lsh[3][cl]);
        lse_upd4(mm, ss, Lsh[4][cl], Lsh[5][cl], Lsh[6][cl], Lsh[7][cl]);
        g[col] = log_a2 - (mm + flog2(ss));
    }
}

// ---------------- T = exp2(f + S + g), in place; global sum == 1 analytically ------
// note: no __restrict__ on S/out — they alias (in-place)
__global__ __launch_bounds__(256) void write_pass(const float* S,
                                                  const float* __restrict__ f,
                                                  const float* __restrict__ g,
                                                  float* out) {
    const int wv = threadIdx.x >> 6, lane = threadIdx.x & 63;
    const int row = blockIdx.x * 4 + wv;
    const float fi = f[row];
    const float4* Sr = (const float4*)(S + (size_t)row * NR);
    const float4* gr = (const float4*)g;
    float4* Or = (float4*)(out + (size_t)row * NR);
#pragma unroll 4
    for (int it = 0; it < NR / 256; ++it) {
        const int idx = it * 64 + lane;
        float4 sv = Sr[idx];
        float4 gv = gr[idx];
        float4 o;
        o.x = fexp2(fi + sv.x + gv.x);
        o.y = fexp2(fi + sv.y + gv.y);
        o.z = fexp2(fi + sv.z + gv.z);
        o.w = fexp2(fi + sv.w + gv.w);
        Or[idx] = o;
    }
}

extern "C" void kernel_launch(void* const* d_in, const int* in_sizes, int n_in,
                              void* d_out, int out_size, void* d_ws, size_t ws_size,
                              hipStream_t stream) {
    (void)in_sizes; (void)n_in; (void)out_size; (void)ws_size;
    const float* A  = (const float*)d_in[0];
    const float* Tk = (const float*)d_in[1];
    const float* Wq = (const float*)d_in[2];
    const float* bq = (const float*)d_in[3];
    const float* Wk = (const float*)d_in[4];
    const float* bk = (const float*)d_in[5];
    const float* W1 = (const float*)d_in[6];
    const float* b1 = (const float*)d_in[7];
    const float* W2 = (const float*)d_in[8];
    const float* b2 = (const float*)d_in[9];
    float* S  = (float*)d_out;           // 8192x8192 base-2 log_K lives in d_out
    float* ws = (float*)d_ws;
    float* qn     = ws; ws += NR;
    float* kn     = ws; ws += NR;
    float* logb2  = ws; ws += NR;
    float* logits = ws; ws += NR;
    float* f      = ws; ws += NR;
    float* g      = ws; ws += NR;
    float* pm     = ws; ws += (size_t)NBLK * NR;   // 16 MB
    float* q      = ws; ws += (size_t)NR * DIM;    // 8 MB
    float* k      = ws; ws += (size_t)NR * DIM;    // 8 MB
    // bf16 split arrays overlay pm (16.78 MB == 4 x NR*DIM ushorts): they are
    // dead once dist_mfma finishes, before the first iter_fused writes pm.
    ushort_t* qh = (ushort_t*)pm;
    ushort_t* ql = qh + (size_t)NR * DIM;
    ushort_t* kh = ql + (size_t)NR * DIM;
    ushort_t* kl = kh + (size_t)NR * DIM;

    const float log_a2 = -13.0f; // log2(1/8192 + 1e-20)

    init_zero<<<32, 256, 0, stream>>>(g);
    gemm_qk2<<<dim3(128, 4, 2), 256, 0, stream>>>(A, Wq, bq, q, Tk, Wk, bk, k);
    row_norm2<<<2 * NR, 64, 0, stream>>>(q, qn, k, kn);
    split_bf16_2<<<2 * (NR * DIM / 1024), 256, 0, stream>>>(q, qh, ql, k, kh, kl);
    mlp_logits<<<NR, 128, 0, stream>>>(A, W1, b1, W2, b2, logits);
    softmax_logb<<<1, 1024, 0, stream>>>(logits, logb2);
    dist_mfma<<<dim3(64, 64), 256, 0, stream>>>(qh, ql, kh, kl, qn, kn, S);
    for (int it = 0; it < 50; ++it) {
        iter_fused<<<NBLK, 512, 0, stream>>>(S, g, logb2, f, pm);
        col_combine<<<NR / 32, 256, 0, stream>>>(pm, g, log_a2);
    }
    write_pass<<<NR / 4, 256, 0, stream>>>(S, f, g, S);
}

// Round 11
// 3421.543 us; speedup vs baseline: 1.0647x; 1.0103x over previous
//
#include <hip/hip_runtime.h>
#include <math.h>

#define NR 8192      // NA == NT
#define DIM 256
#define NBLK 512     // fused-kernel blocks == column-partial chunks (2 per CU)
#define CROWS 16     // rows per chunk
#define RSC 2        // rows per sub-chunk
#define NSUB 8       // sub-chunks per chunk
// 10 * log2(e): converts distances directly into base-2 log domain
#define SCALE2 14.426950408889634f

typedef unsigned short ushort_t;
typedef __attribute__((ext_vector_type(8))) short bfrag;   // 8 bf16 (4 VGPRs)
typedef __attribute__((ext_vector_type(4))) float facc;    // 4 fp32 acc

// v_exp_f32 / v_log_f32 are base-2 natively — use them raw
__device__ __forceinline__ float fexp2(float x) {
#if __has_builtin(__builtin_amdgcn_exp2f)
    return __builtin_amdgcn_exp2f(x);
#else
    return exp2f(x);
#endif
}
__device__ __forceinline__ float flog2(float x) {
#if __has_builtin(__builtin_amdgcn_logf)
    return __builtin_amdgcn_logf(x);
#else
    return log2f(x);
#endif
}

// async global->LDS copy, 16 B per lane, no transit VGPRs.
__device__ __forceinline__ void gl2lds16(const float* gp, float* lp) {
#if __has_builtin(__builtin_amdgcn_global_load_lds)
    __builtin_amdgcn_global_load_lds(
        (const __attribute__((address_space(1))) unsigned int*)gp,
        (__attribute__((address_space(3))) unsigned int*)lp, 16, 0, 0);
#else
    *(float4*)lp = *(const float4*)gp;   // fallback: callers pass lane-adjusted ptrs
#endif
}

// raw waits/barrier: barrier WITHOUT vmcnt(0) drain; explicit vmcnt gate.
__device__ __forceinline__ void wait_vm0()  { asm volatile("s_waitcnt vmcnt(0)" ::: "memory"); }
__device__ __forceinline__ void bar_lgkm()  { asm volatile("s_waitcnt lgkmcnt(0)\ns_barrier" ::: "memory"); }

// base-2 online LSE combine
__device__ __forceinline__ void lse_comb2(float& m, float& s, float mo, float so) {
    float nm = fmaxf(m, mo);
    s = s * fexp2(m - nm) + so * fexp2(mo - nm);
    m = nm;
}

// grouped-4 online LSE update (1 tree-max + 1 correction exp per 4 values)
__device__ __forceinline__ void lse_upd4(float& m, float& s,
                                         float v0, float v1, float v2, float v3) {
    float m4 = fmaxf(fmaxf(v0, v1), fmaxf(v2, v3));
    float nm = fmaxf(m, m4);
    float e = fexp2(v0 - nm) + fexp2(v1 - nm) + fexp2(v2 - nm) + fexp2(v3 - nm);
    s = fmaf(s, fexp2(m - nm), e);
    m = nm;
}

// grouped-2 online LSE update
__device__ __forceinline__ void lse_upd2(float& m, float& s, float v0, float v1) {
    float m2 = fmaxf(v0, v1);
    float nm = fmaxf(m, m2);
    float e = fexp2(v0 - nm) + fexp2(v1 - nm);
    s = fmaf(s, fexp2(m - nm), e);
    m = nm;
}

// RNE float -> bf16 bits (manual: deterministic, no API variance)
__device__ __forceinline__ ushort_t f2bf(float x) {
    unsigned u = __float_as_uint(x);
    u += 0x7FFFu + ((u >> 16) & 1u);
    return (ushort_t)(u >> 16);
}
__device__ __forceinline__ float bf2f(ushort_t b) {
    return __uint_as_float(((unsigned)b) << 16);
}

// ---------------- init ----------------
__global__ void init_zero(float* __restrict__ g) {
    int t = blockIdx.x * 256 + threadIdx.x;
    if (t < NR) g[t] = 0.0f;
}

// ---------------- out[M,DIM] = A[M,DIM] @ W[DIM,DIM] + bias (2 problems, z-dim) ----
__global__ __launch_bounds__(256) void gemm_qk2(const float* __restrict__ A0,
                                                const float* __restrict__ W0,
                                                const float* __restrict__ bias0,
                                                float* __restrict__ out0,
                                                const float* __restrict__ A1,
                                                const float* __restrict__ W1,
                                                const float* __restrict__ bias1,
                                                float* __restrict__ out1) {
    const float* A    = blockIdx.z ? A1 : A0;
    const float* W    = blockIdx.z ? W1 : W0;
    const float* bias = blockIdx.z ? bias1 : bias0;
    float* out        = blockIdx.z ? out1 : out0;
    __shared__ float As[16][68];
    __shared__ float Ws[16][68];
    const int t  = threadIdx.x;
    const int r0 = blockIdx.x * 64;
    const int c0 = blockIdx.y * 64;
    const int ty = t >> 4, tx = t & 15;
    const int arow = t >> 2;
    const int ak   = (t & 3) * 4;
    const int wrow = t >> 4;
    const int wcol = (t & 15) * 4;
    float acc[4][4] = {};
    for (int k0 = 0; k0 < DIM; k0 += 16) {
        float4 av = *(const float4*)(A + (size_t)(r0 + arow) * DIM + k0 + ak);
        float4 wv = *(const float4*)(W + (size_t)(k0 + wrow) * DIM + c0 + wcol);
        __syncthreads();
        As[ak + 0][arow] = av.x; As[ak + 1][arow] = av.y;
        As[ak + 2][arow] = av.z; As[ak + 3][arow] = av.w;
        *(float4*)&Ws[wrow][wcol] = wv;
        __syncthreads();
#pragma unroll
        for (int kk = 0; kk < 16; ++kk) {
            float4 a = *(const float4*)&As[kk][ty * 4];
            float4 b = *(const float4*)&Ws[kk][tx * 4];
            float aa[4] = {a.x, a.y, a.z, a.w};
            float bb[4] = {b.x, b.y, b.z, b.w};
#pragma unroll
            for (int i = 0; i < 4; ++i)
#pragma unroll
                for (int j = 0; j < 4; ++j)
                    acc[i][j] = fmaf(aa[i], bb[j], acc[i][j]);
        }
    }
#pragma unroll
    for (int i = 0; i < 4; ++i) {
        float4 o;
        o.x = acc[i][0] + bias[c0 + tx * 4 + 0];
        o.y = acc[i][1] + bias[c0 + tx * 4 + 1];
        o.z = acc[i][2] + bias[c0 + tx * 4 + 2];
        o.w = acc[i][3] + bias[c0 + tx * 4 + 3];
        *(float4*)(out + (size_t)(r0 + ty * 4 + i) * DIM + c0 + tx * 4) = o;
    }
}

// ---------------- row squared norms (q and k in one launch) ----------------
__global__ __launch_bounds__(64) void row_norm2(const float* __restrict__ q,
                                                float* __restrict__ qn,
                                                const float* __restrict__ k,
                                                float* __restrict__ kn) {
    const int sel = blockIdx.x >> 13;          // 0: q, 1: k (8192 blocks each)
    const int row = blockIdx.x & (NR - 1);
    const int lane = threadIdx.x;
    const float* x = sel ? k : q;
    float* out     = sel ? kn : qn;
    float4 v = *(const float4*)(x + (size_t)row * DIM + lane * 4);
    float s = v.x * v.x + v.y * v.y + v.z * v.z + v.w * v.w;
#pragma unroll
    for (int off = 32; off > 0; off >>= 1) s += __shfl_xor(s, off);
    if (lane == 0) out[row] = s;
}

// ---------------- split fp32 -> bf16 hi + lo, q and k in one launch --------------
__global__ __launch_bounds__(256) void split_bf16_2(const float* __restrict__ q,
                                                    ushort_t* __restrict__ qh,
                                                    ushort_t* __restrict__ ql,
                                                    const float* __restrict__ k,
                                                    ushort_t* __restrict__ kh,
                                                    ushort_t* __restrict__ kl) {
    const int sel = blockIdx.x >> 11;          // 2048 blocks per problem
    const int b = blockIdx.x & 2047;
    const float* x = sel ? k : q;
    ushort_t* hi   = sel ? kh : qh;
    ushort_t* lo   = sel ? kl : ql;
    const int idx = (b * 256 + threadIdx.x) * 4;
    float4 v = *(const float4*)(x + idx);
    ushort_t h0 = f2bf(v.x), h1 = f2bf(v.y), h2 = f2bf(v.z), h3 = f2bf(v.w);
    ushort4 hv = make_ushort4(h0, h1, h2, h3);
    ushort4 lv = make_ushort4(f2bf(v.x - bf2f(h0)), f2bf(v.y - bf2f(h1)),
                              f2bf(v.z - bf2f(h2)), f2bf(v.w - bf2f(h3)));
    *(ushort4*)(hi + idx) = hv;
    *(ushort4*)(lo + idx) = lv;
}

// ---------------- S = SCALE2*(qn_i + kn_j - 2*q_i.k_j) via split-bf16 MFMA ----------
// R11: restored to the R8-proven form (rolled k0 loop, natural MFMA order,
// natural block order). R9's XCD swizzle (4.3x FETCH, no speedup) and R10's
// unroll+product-major reorder (+7 us, MfmaUtil unchanged) both failed —
// the kernel is issue/latency-bound in a way neither addressed.
__global__ __launch_bounds__(256) void dist_mfma(const ushort_t* __restrict__ qh,
                                                 const ushort_t* __restrict__ ql,
                                                 const ushort_t* __restrict__ kh,
                                                 const ushort_t* __restrict__ kl,
                                                 const float* __restrict__ qn,
                                                 const float* __restrict__ kn,
                                                 float* __restrict__ S) {
    const int t = threadIdx.x;
    const int wv = t >> 6, lane = t & 63;
    const int r0 = blockIdx.y * 128 + (wv >> 1) * 64;
    const int c0 = blockIdx.x * 128 + (wv & 1) * 64;
    const int fr = lane & 15;       // row (A) / col (B) within 16x16 tile
    const int fq = lane >> 4;       // quad -> k-subrange / C-row group
    facc acc[4][4];
#pragma unroll
    for (int i = 0; i < 4; ++i)
#pragma unroll
        for (int j = 0; j < 4; ++j) acc[i][j] = (facc){0.f, 0.f, 0.f, 0.f};

    for (int k0 = 0; k0 < DIM; k0 += 32) {
        const int ks = k0 + fq * 8;
        bfrag ah[4], al[4], bh[4], bl[4];
#pragma unroll
        for (int mi = 0; mi < 4; ++mi) {
            const size_t ao = (size_t)(r0 + mi * 16 + fr) * DIM + ks;
            ah[mi] = *(const bfrag*)(qh + ao);
            al[mi] = *(const bfrag*)(ql + ao);
        }
#pragma unroll
        for (int ni = 0; ni < 4; ++ni) {
            const size_t bo = (size_t)(c0 + ni * 16 + fr) * DIM + ks;
            bh[ni] = *(const bfrag*)(kh + bo);
            bl[ni] = *(const bfrag*)(kl + bo);
        }
#pragma unroll
        for (int mi = 0; mi < 4; ++mi)
#pragma unroll
            for (int ni = 0; ni < 4; ++ni) {
                acc[mi][ni] = __builtin_amdgcn_mfma_f32_16x16x32_bf16(ah[mi], bh[ni], acc[mi][ni], 0, 0, 0);
                acc[mi][ni] = __builtin_amdgcn_mfma_f32_16x16x32_bf16(ah[mi], bl[ni], acc[mi][ni], 0, 0, 0);
                acc[mi][ni] = __builtin_amdgcn_mfma_f32_16x16x32_bf16(al[mi], bh[ni], acc[mi][ni], 0, 0, 0);
                acc[mi][ni] = __builtin_amdgcn_mfma_f32_16x16x32_bf16(al[mi], bl[ni], acc[mi][ni], 0, 0, 0);
            }
    }
    // epilogue: S[row][col] = (qn + kn - 2*dot) * SCALE2
#pragma unroll
    for (int mi = 0; mi < 4; ++mi) {
        float qnr[4];
#pragma unroll
        for (int r = 0; r < 4; ++r) qnr[r] = qn[r0 + mi * 16 + fq * 4 + r];
#pragma unroll
        for (int ni = 0; ni < 4; ++ni) {
            const int col = c0 + ni * 16 + fr;
            const float knc = kn[col];
#pragma unroll
            for (int r = 0; r < 4; ++r) {
                const int row = r0 + mi * 16 + fq * 4 + r;
                S[(size_t)row * NR + col] = (qnr[r] + knc - 2.0f * acc[mi][ni][r]) * SCALE2;
            }
        }
    }
}

// ---------------- MLP logits: relu(A@W1+b1)@W2 + b2 ----------------
__global__ __launch_bounds__(128) void mlp_logits(const float* __restrict__ A,
                                                  const float* __restrict__ W1,
                                                  const float* __restrict__ b1,
                                                  const float* __restrict__ W2,
                                                  const float* __restrict__ b2,
                                                  float* __restrict__ logits) {
    __shared__ float ar[DIM];
    __shared__ float red[2];
    const int t = threadIdx.x;
    const int row = blockIdx.x;
    *(float2*)&ar[t * 2] = *(const float2*)(A + (size_t)row * DIM + t * 2);
    __syncthreads();
    float h = b1[t];
#pragma unroll 8
    for (int kk = 0; kk < DIM; ++kk) h = fmaf(ar[kk], W1[kk * 128 + t], h);
    float val = fmaxf(h, 0.0f) * W2[t];
#pragma unroll
    for (int off = 32; off > 0; off >>= 1) val += __shfl_xor(val, off);
    if ((t & 63) == 0) red[t >> 6] = val;
    __syncthreads();
    if (t == 0) logits[row] = red[0] + red[1] + b2[0];
}

// ---------------- softmax over 8192 logits -> log2(b + 1e-20) ----------------
__global__ __launch_bounds__(1024) void softmax_logb(const float* __restrict__ logits,
                                                     float* __restrict__ logb2) {
    __shared__ float redm[16], reds[16];
    const int t = threadIdx.x;
    float l[8];
    float m = -INFINITY;
#pragma unroll
    for (int i = 0; i < 8; ++i) { l[i] = logits[i * 1024 + t]; m = fmaxf(m, l[i]); }
#pragma unroll
    for (int off = 32; off > 0; off >>= 1) m = fmaxf(m, __shfl_xor(m, off));
    if ((t & 63) == 0) redm[t >> 6] = m;
    __syncthreads();
    if (t < 64) {
        float v = (t < 16) ? redm[t] : -INFINITY;
#pragma unroll
        for (int off = 8; off > 0; off >>= 1) v = fmaxf(v, __shfl_xor(v, off));
        if (t == 0) redm[0] = v;
    }
    __syncthreads();
    m = redm[0];
    float s = 0.0f;
#pragma unroll
    for (int i = 0; i < 8; ++i) s += __expf(l[i] - m);
#pragma unroll
    for (int off = 32; off > 0; off >>= 1) s += __shfl_xor(s, off);
    if ((t & 63) == 0) reds[t >> 6] = s;
    __syncthreads();
    if (t < 64) {
        float v = (t < 16) ? reds[t] : 0.0f;
#pragma unroll
        for (int off = 8; off > 0; off >>= 1) v += __shfl_xor(v, off);
        if (t == 0) reds[0] = v;
    }
    __syncthreads();
    s = reds[0];
    float invs = 1.0f / s;
#pragma unroll
    for (int i = 0; i < 8; ++i)
        logb2[i * 1024 + t] = log2f(__expf(l[i] - m) * invs + 1e-20f);
}

// ---------------- fused iteration: DMA staging + 2 blocks/CU overlap ----------------
// (R0-proven structure: 54 us/iter, VGPR=64, zero scratch.)
__global__ __launch_bounds__(512, 4) void iter_fused(const float* __restrict__ S,
                                                     const float* __restrict__ g,
                                                     const float* __restrict__ logb2,
                                                     float* __restrict__ f,
                                                     float* __restrict__ pm) {
    __shared__ float buf[RSC][NR];      // 64 KB staging (single buffer)
    __shared__ float redm[8], reds[8];
    const int t = threadIdx.x;
    const int wv = t >> 6, lane = t & 63;
    const int chunk = blockIdx.x;
    const int r0 = chunk * CROWS;
    const int rw = wv >> 2;             // row (0..1) within sub-chunk
    const int qt = wv & 3;              // quarter of the row this wave handles
    const int qbase = qt * 2048;
    const int loff = lane * 4;

    // preload this wave's g quarter (constant within one launch): 8 float4
    float4 greg[8];
#pragma unroll
    for (int it = 0; it < 8; ++it)
        greg[it] = *(const float4*)(g + qbase + it * 256 + loff);

    // column accumulators: thread t owns cols {j*2048 + t*4 + c}
    float cm[4][4], cs[4][4];
#pragma unroll
    for (int j = 0; j < 4; ++j)
#pragma unroll
        for (int c = 0; c < 4; ++c) { cm[j][c] = -INFINITY; cs[j][c] = 0.0f; }

    // prologue: DMA sub-chunk 0
    {
        const float* Sr = S + (size_t)(r0 + rw) * NR + qbase;
        float* ld = &buf[rw][qbase];
#pragma unroll
        for (int it = 0; it < 8; ++it)
#if __has_builtin(__builtin_amdgcn_global_load_lds)
            gl2lds16(Sr + it * 256 + loff, ld + it * 256);
#else
            gl2lds16(Sr + it * 256 + loff, ld + it * 256 + loff);
#endif
    }

    for (int sc = 0; sc < NSUB; ++sc) {
        wait_vm0();   // own DMA(sc) (and greg/f stragglers) complete
        // ---- phase 1: row-LSE over this wave's quarter (LDS + g regs) ----
        float m = -INFINITY, s = 0.0f;
#pragma unroll
        for (int it = 0; it < 8; ++it) {
            float4 v = *(const float4*)&buf[rw][qbase + it * 256 + loff];
            float4 gv = greg[it];
            lse_upd4(m, s, v.x + gv.x, v.y + gv.y, v.z + gv.z, v.w + gv.w);
        }
#pragma unroll
        for (int off = 32; off > 0; off >>= 1) {
            float mo = __shfl_xor(m, off);
            float so = __shfl_xor(s, off);
            lse_comb2(m, s, mo, so);
        }
        if (lane == 0) { redm[wv] = m; reds[wv] = s; }
        bar_lgkm();   // barrier A: all DMA(sc) complete block-wide; red visible

        // ---- all threads: combine 4 quarter partials per row -> f0, f1 ----
        float fr[RSC];
#pragma unroll
        for (int r = 0; r < RSC; ++r) {
            float mm = redm[r * 4 + 0], ss = reds[r * 4 + 0];
            lse_comb2(mm, ss, redm[r * 4 + 1], reds[r * 4 + 1]);
            lse_comb2(mm, ss, redm[r * 4 + 2], reds[r * 4 + 2]);
            lse_comb2(mm, ss, redm[r * 4 + 3], reds[r * 4 + 3]);
            fr[r] = logb2[r0 + sc * RSC + r] - (mm + flog2(ss));
        }
        if (t < RSC) f[r0 + sc * RSC + t] = fr[t];

        // ---- phase 2: column partial-LSE over the 2 staged rows (LDS) ----
#pragma unroll
        for (int j = 0; j < 4; ++j) {
            const int c = j * 2048 + t * 4;
            float4 a = *(const float4*)&buf[0][c];
            float4 bb = *(const float4*)&buf[1][c];
            lse_upd2(cm[j][0], cs[j][0], a.x + fr[0], bb.x + fr[1]);
            lse_upd2(cm[j][1], cs[j][1], a.y + fr[0], bb.y + fr[1]);
            lse_upd2(cm[j][2], cs[j][2], a.z + fr[0], bb.z + fr[1]);
            lse_upd2(cm[j][3], cs[j][3], a.w + fr[0], bb.w + fr[1]);
        }
        bar_lgkm();   // barrier B: every wave done reading buf

        // ---- issue DMA for sub-chunk sc+1 (safe: all reads of buf finished) ----
        if (sc + 1 < NSUB) {
            const float* Sn = S + (size_t)(r0 + (sc + 1) * RSC + rw) * NR + qbase;
            float* ld = &buf[rw][qbase];
#pragma unroll
            for (int it = 0; it < 8; ++it)
#if __has_builtin(__builtin_amdgcn_global_load_lds)
                gl2lds16(Sn + it * 256 + loff, ld + it * 256);
#else
                gl2lds16(Sn + it * 256 + loff, ld + it * 256 + loff);
#endif
        }
    }
    // write column partials for this chunk as a single float L = m + log2(s)
#pragma unroll
    for (int j = 0; j < 4; ++j) {
        float4 L;
        L.x = cm[j][0] + flog2(cs[j][0]);
        L.y = cm[j][1] + flog2(cs[j][1]);
        L.z = cm[j][2] + flog2(cs[j][2]);
        L.w = cm[j][3] + flog2(cs[j][3]);
        *(float4*)&pm[(size_t)chunk * NR + j * 2048 + t * 4] = L;
    }
}

// ---------------- combine partials -> g (256 blocks x 1024 threads) ----------------
// R11: same coalesced column layout as the R8 version (lanes 0-31 cover 32
// consecutive cols = 128 B per chunk-row), but 4x the TLP: 1024 threads
// (16 waves/CU vs 4) with 32 chunk-groups x 16 chunks. The R8 version was
// latency-bound at 2.7 TB/s precisely because only 4 waves/CU were hiding
// 64 dependent stride-32KB loads per thread.
__global__ __launch_bounds__(1024) void col_combine(const float* __restrict__ pm,
                                                    float* __restrict__ g,
                                                    float log_a2) {
    __shared__ float Lm[32][32], Ls[32][32];
    __shared__ float Lm2[8][32], Ls2[8][32];
    const int t = threadIdx.x;
    const int cl = t & 31;                 // column within block
    const int grp = t >> 5;                // chunk group (0..31), 16 chunks each
    const int col = blockIdx.x * 32 + cl;
    float m = -INFINITY, s = 0.0f;
#pragma unroll
    for (int i = 0; i < 16; i += 4) {
        float l0 = pm[(size_t)(grp * 16 + i + 0) * NR + col];
        float l1 = pm[(size_t)(grp * 16 + i + 1) * NR + col];
        float l2 = pm[(size_t)(grp * 16 + i + 2) * NR + col];
        float l3 = pm[(size_t)(grp * 16 + i + 3) * NR + col];
        lse_upd4(m, s, l0, l1, l2, l3);
    }
    Lm[grp][cl] = m; Ls[grp][cl] = s;
    __syncthreads();
    if (t < 256) {
        const int c = t & 31, q = t >> 5;  // 8 quads of 4 groups
        float mm = Lm[q * 4 + 0][c], ss = Ls[q * 4 + 0][c];
        lse_comb2(mm, ss, Lm[q * 4 + 1][c], Ls[q * 4 + 1][c]);
        lse_comb2(mm, ss, Lm[q * 4 + 2][c], Ls[q * 4 + 2][c]);
        lse_comb2(mm, ss, Lm[q * 4 + 3][c], Ls[q * 4 + 3][c]);
        Lm2[q][c] = mm; Ls2[q][c] = ss;
    }
    __syncthreads();
    if (t < 32) {
        float mm = Lm2[0][t], ss = Ls2[0][t];
#pragma unroll
        for (int q = 1; q < 8; ++q) lse_comb2(mm, ss, Lm2[q][t], Ls2[q][t]);
        g[blockIdx.x * 32 + t] = log_a2 - (mm + flog2(ss));
    }
}

// ---------------- T = exp2(f + S + g), in place; global sum == 1 analytically ------
// note: no __restrict__ on S/out — they alias (in-place)
__global__ __launch_bounds__(256) void write_pass(const float* S,
                                                  const float* __restrict__ f,
                                                  const float* __restrict__ g,
                                                  float* out) {
    const int wv = threadIdx.x >> 6, lane = threadIdx.x & 63;
    const int row = blockIdx.x * 4 + wv;
    const float fi = f[row];
    const float4* Sr = (const float4*)(S + (size_t)row * NR);
    const float4* gr = (const float4*)g;
    float4* Or = (float4*)(out + (size_t)row * NR);
#pragma unroll 4
    for (int it = 0; it < NR / 256; ++it) {
        const int idx = it * 64 + lane;
        float4 sv = Sr[idx];
        float4 gv = gr[idx];
        float4 o;
        o.x = fexp2(fi + sv.x + gv.x);
        o.y = fexp2(fi + sv.y + gv.y);
        o.z = fexp2(fi + sv.z + gv.z);
        o.w = fexp2(fi + sv.w + gv.w);
        Or[idx] = o;
    }
}

extern "C" void kernel_launch(void* const* d_in, const int* in_sizes, int n_in,
                              void* d_out, int out_size, void* d_ws, size_t ws_size,
                              hipStream_t stream) {
    (void)in_sizes; (void)n_in; (void)out_size; (void)ws_size;
    const float* A  = (const float*)d_in[0];
    const float* Tk = (const float*)d_in[1];
    const float* Wq = (const float*)d_in[2];
    const float* bq = (const float*)d_in[3];
    const float* Wk = (const float*)d_in[4];
    const float* bk = (const float*)d_in[5];
    const float* W1 = (const float*)d_in[6];
    const float* b1 = (const float*)d_in[7];
    const float* W2 = (const float*)d_in[8];
    const float* b2 = (const float*)d_in[9];
    float* S  = (float*)d_out;           // 8192x8192 base-2 log_K lives in d_out
    float* ws = (float*)d_ws;
    float* qn     = ws; ws += NR;
    float* kn     = ws; ws += NR;
    float* logb2  = ws; ws += NR;
    float* logits = ws; ws += NR;
    float* f      = ws; ws += NR;
    float* g      = ws; ws += NR;
    float* pm     = ws; ws += (size_t)NBLK * NR;   // 16 MB
    float* q      = ws; ws += (size_t)NR * DIM;    // 8 MB
    float* k      = ws; ws += (size_t)NR * DIM;    // 8 MB
    // bf16 split arrays overlay pm (16.78 MB == 4 x NR*DIM ushorts): they are
    // dead once dist_mfma finishes, before the first iter_fused writes pm.
    ushort_t* qh = (ushort_t*)pm;
    ushort_t* ql = qh + (size_t)NR * DIM;
    ushort_t* kh = ql + (size_t)NR * DIM;
    ushort_t* kl = kh + (size_t)NR * DIM;

    const float log_a2 = -13.0f; // log2(1/8192 + 1e-20)

    init_zero<<<32, 256, 0, stream>>>(g);
    gemm_qk2<<<dim3(128, 4, 2), 256, 0, stream>>>(A, Wq, bq, q, Tk, Wk, bk, k);
    row_norm2<<<2 * NR, 64, 0, stream>>>(q, qn, k, kn);
    split_bf16_2<<<2 * (NR * DIM / 1024), 256, 0, stream>>>(q, qh, ql, k, kh, kl);
    mlp_logits<<<NR, 128, 0, stream>>>(A, W1, b1, W2, b2, logits);
    softmax_logb<<<1, 1024, 0, stream>>>(logits, logb2);
    dist_mfma<<<dim3(64, 64), 256, 0, stream>>>(qh, ql, kh, kl, qn, kn, S);
    for (int it = 0; it < 50; ++it) {
        iter_fused<<<NBLK, 512, 0, stream>>>(S, g, logb2, f, pm);
        col_combine<<<NR / 32, 1024, 0, stream>>>(pm, g, log_a2);
    }
    write_pass<<<NR / 4, 256, 0, stream>>>(S, f, g, S);
}

// Round 12
// 3334.317 us; speedup vs baseline: 1.0925x; 1.0262x over previous
//
#include <hip/hip_runtime.h>
#include <math.h>

#define NR 8192      // NA == NT
#define DIM 256
#define NBLK 512     // fused-kernel blocks == column-partial chunks (2 per CU)
#define CROWS 16     // rows per chunk
#define RSC 2        // rows per sub-chunk
#define NSUB 8       // sub-chunks per chunk
// 10 * log2(e): converts distances directly into base-2 log domain
#define SCALE2 14.426950408889634f
// chunk swizzle for 64B LDS rows: spreads ds_read_b128 across bank quads
#define SW3(r) ((((r) >> 2) ^ (r)) & 3)

typedef unsigned short ushort_t;
typedef __attribute__((ext_vector_type(8))) short bfrag;   // 8 bf16 (4 VGPRs)
typedef __attribute__((ext_vector_type(4))) float facc;    // 4 fp32 acc

// v_exp_f32 / v_log_f32 are base-2 natively — use them raw
__device__ __forceinline__ float fexp2(float x) {
#if __has_builtin(__builtin_amdgcn_exp2f)
    return __builtin_amdgcn_exp2f(x);
#else
    return exp2f(x);
#endif
}
__device__ __forceinline__ float flog2(float x) {
#if __has_builtin(__builtin_amdgcn_logf)
    return __builtin_amdgcn_logf(x);
#else
    return log2f(x);
#endif
}

// async global->LDS copy, 16 B per lane, no transit VGPRs.
__device__ __forceinline__ void gl2lds16(const float* gp, float* lp) {
#if __has_builtin(__builtin_amdgcn_global_load_lds)
    __builtin_amdgcn_global_load_lds(
        (const __attribute__((address_space(1))) unsigned int*)gp,
        (__attribute__((address_space(3))) unsigned int*)lp, 16, 0, 0);
#else
    *(float4*)lp = *(const float4*)gp;   // fallback: callers pass lane-adjusted ptrs
#endif
}
__device__ __forceinline__ void gl2lds16u(const ushort_t* gp, ushort_t* lp) {
#if __has_builtin(__builtin_amdgcn_global_load_lds)
    __builtin_amdgcn_global_load_lds(
        (const __attribute__((address_space(1))) unsigned int*)gp,
        (__attribute__((address_space(3))) unsigned int*)lp, 16, 0, 0);
#else
    *(float4*)lp = *(const float4*)gp;   // fallback: callers pass lane-adjusted ptrs
#endif
}

// raw waits/barrier: barrier WITHOUT vmcnt(0) drain; explicit vmcnt gate.
__device__ __forceinline__ void wait_vm0()  { asm volatile("s_waitcnt vmcnt(0)" ::: "memory"); }
__device__ __forceinline__ void bar_lgkm()  { asm volatile("s_waitcnt lgkmcnt(0)\ns_barrier" ::: "memory"); }

// base-2 online LSE combine
__device__ __forceinline__ void lse_comb2(float& m, float& s, float mo, float so) {
    float nm = fmaxf(m, mo);
    s = s * fexp2(m - nm) + so * fexp2(mo - nm);
    m = nm;
}

// grouped-4 online LSE update (1 tree-max + 1 correction exp per 4 values)
__device__ __forceinline__ void lse_upd4(float& m, float& s,
                                         float v0, float v1, float v2, float v3) {
    float m4 = fmaxf(fmaxf(v0, v1), fmaxf(v2, v3));
    float nm = fmaxf(m, m4);
    float e = fexp2(v0 - nm) + fexp2(v1 - nm) + fexp2(v2 - nm) + fexp2(v3 - nm);
    s = fmaf(s, fexp2(m - nm), e);
    m = nm;
}

// grouped-2 online LSE update
__device__ __forceinline__ void lse_upd2(float& m, float& s, float v0, float v1) {
    float m2 = fmaxf(v0, v1);
    float nm = fmaxf(m, m2);
    float e = fexp2(v0 - nm) + fexp2(v1 - nm);
    s = fmaf(s, fexp2(m - nm), e);
    m = nm;
}

// RNE float -> bf16 bits (manual: deterministic, no API variance)
__device__ __forceinline__ ushort_t f2bf(float x) {
    unsigned u = __float_as_uint(x);
    u += 0x7FFFu + ((u >> 16) & 1u);
    return (ushort_t)(u >> 16);
}
__device__ __forceinline__ float bf2f(ushort_t b) {
    return __uint_as_float(((unsigned)b) << 16);
}

// ---------------- init ----------------
__global__ void init_zero(float* __restrict__ g) {
    int t = blockIdx.x * 256 + threadIdx.x;
    if (t < NR) g[t] = 0.0f;
}

// ---------------- out[M,DIM] = A[M,DIM] @ W[DIM,DIM] + bias (2 problems, z-dim) ----
__global__ __launch_bounds__(256) void gemm_qk2(const float* __restrict__ A0,
                                                const float* __restrict__ W0,
                                                const float* __restrict__ bias0,
                                                float* __restrict__ out0,
                                                const float* __restrict__ A1,
                                                const float* __restrict__ W1,
                                                const float* __restrict__ bias1,
                                                float* __restrict__ out1) {
    const float* A    = blockIdx.z ? A1 : A0;
    const float* W    = blockIdx.z ? W1 : W0;
    const float* bias = blockIdx.z ? bias1 : bias0;
    float* out        = blockIdx.z ? out1 : out0;
    __shared__ float As[16][68];
    __shared__ float Ws[16][68];
    const int t  = threadIdx.x;
    const int r0 = blockIdx.x * 64;
    const int c0 = blockIdx.y * 64;
    const int ty = t >> 4, tx = t & 15;
    const int arow = t >> 2;
    const int ak   = (t & 3) * 4;
    const int wrow = t >> 4;
    const int wcol = (t & 15) * 4;
    float acc[4][4] = {};
    for (int k0 = 0; k0 < DIM; k0 += 16) {
        float4 av = *(const float4*)(A + (size_t)(r0 + arow) * DIM + k0 + ak);
        float4 wv = *(const float4*)(W + (size_t)(k0 + wrow) * DIM + c0 + wcol);
        __syncthreads();
        As[ak + 0][arow] = av.x; As[ak + 1][arow] = av.y;
        As[ak + 2][arow] = av.z; As[ak + 3][arow] = av.w;
        *(float4*)&Ws[wrow][wcol] = wv;
        __syncthreads();
#pragma unroll
        for (int kk = 0; kk < 16; ++kk) {
            float4 a = *(const float4*)&As[kk][ty * 4];
            float4 b = *(const float4*)&Ws[kk][tx * 4];
            float aa[4] = {a.x, a.y, a.z, a.w};
            float bb[4] = {b.x, b.y, b.z, b.w};
#pragma unroll
            for (int i = 0; i < 4; ++i)
#pragma unroll
                for (int j = 0; j < 4; ++j)
                    acc[i][j] = fmaf(aa[i], bb[j], acc[i][j]);
        }
    }
#pragma unroll
    for (int i = 0; i < 4; ++i) {
        float4 o;
        o.x = acc[i][0] + bias[c0 + tx * 4 + 0];
        o.y = acc[i][1] + bias[c0 + tx * 4 + 1];
        o.z = acc[i][2] + bias[c0 + tx * 4 + 2];
        o.w = acc[i][3] + bias[c0 + tx * 4 + 3];
        *(float4*)(out + (size_t)(r0 + ty * 4 + i) * DIM + c0 + tx * 4) = o;
    }
}

// ---------------- row squared norms (q and k in one launch) ----------------
__global__ __launch_bounds__(64) void row_norm2(const float* __restrict__ q,
                                                float* __restrict__ qn,
                                                const float* __restrict__ k,
                                                float* __restrict__ kn) {
    const int sel = blockIdx.x >> 13;          // 0: q, 1: k (8192 blocks each)
    const int row = blockIdx.x & (NR - 1);
    const int lane = threadIdx.x;
    const float* x = sel ? k : q;
    float* out     = sel ? kn : qn;
    float4 v = *(const float4*)(x + (size_t)row * DIM + lane * 4);
    float s = v.x * v.x + v.y * v.y + v.z * v.z + v.w * v.w;
#pragma unroll
    for (int off = 32; off > 0; off >>= 1) s += __shfl_xor(s, off);
    if (lane == 0) out[row] = s;
}

// ---------------- split fp32 -> bf16 hi + lo, q and k in one launch --------------
__global__ __launch_bounds__(256) void split_bf16_2(const float* __restrict__ q,
                                                    ushort_t* __restrict__ qh,
                                                    ushort_t* __restrict__ ql,
                                                    const float* __restrict__ k,
                                                    ushort_t* __restrict__ kh,
                                                    ushort_t* __restrict__ kl) {
    const int sel = blockIdx.x >> 11;          // 2048 blocks per problem
    const int b = blockIdx.x & 2047;
    const float* x = sel ? k : q;
    ushort_t* hi   = sel ? kh : qh;
    ushort_t* lo   = sel ? kl : ql;
    const int idx = (b * 256 + threadIdx.x) * 4;
    float4 v = *(const float4*)(x + idx);
    ushort_t h0 = f2bf(v.x), h1 = f2bf(v.y), h2 = f2bf(v.z), h3 = f2bf(v.w);
    ushort4 hv = make_ushort4(h0, h1, h2, h3);
    ushort4 lv = make_ushort4(f2bf(v.x - bf2f(h0)), f2bf(v.y - bf2f(h1)),
                              f2bf(v.z - bf2f(h2)), f2bf(v.w - bf2f(h3)));
    *(ushort4*)(hi + idx) = hv;
    *(ushort4*)(lo + idx) = lv;
}

// ---------------- S = SCALE2*(qn_i + kn_j - 2*q_i.k_j), LDS-staged MFMA -----------
// R12 (m97-style): R11's direct-from-L2 fragment loads left the kernel
// latency-bound (MfmaUtil 21%, VALU 17%, HBM 15%, occupancy 22% — nothing
// saturated). This version stages Ah/Al/Bh/Bl tiles (128x32 bf16 = 8 KB each,
// 32 KB LDS) via global_load_lds (one tile per wave, 8 x 16B-wide instrs),
// then reads fragments with swizzled ds_read_b128. Rule #21: LDS dest linear,
// global SOURCE pre-swizzled chunk^SW3(row), read side applies the same XOR ->
// uniform 8 lanes/bank-quad (optimal for b128). Products sequenced hh->lh->
// hl->ll reusing fragment regs (peak ~112 VGPR); launch_bounds(256,3) keeps
// the allocator cap ~170 (R4/R5 lesson), 3 blocks/CU.
__global__ __launch_bounds__(256, 3) void dist_mfma(const ushort_t* __restrict__ qh,
                                                    const ushort_t* __restrict__ ql,
                                                    const ushort_t* __restrict__ kh,
                                                    const ushort_t* __restrict__ kl,
                                                    const float* __restrict__ qn,
                                                    const float* __restrict__ kn,
                                                    float* __restrict__ S) {
    __shared__ ushort_t Ah[128 * 32], Al[128 * 32], Bh[128 * 32], Bl[128 * 32];
    const int t = threadIdx.x;
    const int wv = t >> 6, lane = t & 63;
    const int r0 = blockIdx.y * 128;
    const int c0 = blockIdx.x * 128;
    const int fr = lane & 15;       // row (A) / col (B) within 16x16 tile
    const int fq = lane >> 4;       // quad -> k-subrange / C-row group
    const int arow = (wv >> 1) * 64;   // this wave's quadrant (local row base)
    const int brow = (wv & 1) * 64;

    // staging assignment: wave 0->Ah, 1->Al, 2->Bh, 3->Bl
    const ushort_t* gsrc = (wv == 0) ? qh : (wv == 1) ? ql : (wv == 2) ? kh : kl;
    ushort_t* ltile      = (wv == 0) ? Ah : (wv == 1) ? Al : (wv == 2) ? Bh : Bl;
    const int gbase = (wv < 2) ? r0 : c0;
    const int prow = lane >> 2;        // staging row within 16-row group
    const int pchunk = lane & 3;       // staging 16B-chunk within 64B row

    facc acc[4][4];
#pragma unroll
    for (int i = 0; i < 4; ++i)
#pragma unroll
        for (int j = 0; j < 4; ++j) acc[i][j] = (facc){0.f, 0.f, 0.f, 0.f};

    for (int k0 = 0; k0 < DIM; k0 += 32) {
        // ---- stage this wave's 8 KB tile: 8 x 1 KB global_load_lds ----
#pragma unroll
        for (int i = 0; i < 8; ++i) {
            const int row = i * 16 + prow;                 // tile-local row
            const int lchunk = pchunk ^ SW3(row);          // pre-swizzled source
            const ushort_t* sp = gsrc + (size_t)(gbase + row) * DIM + k0 + lchunk * 8;
#if __has_builtin(__builtin_amdgcn_global_load_lds)
            gl2lds16u(sp, ltile + i * 512);
#else
            gl2lds16u(sp, ltile + i * 512 + lane * 8);
#endif
        }
        wait_vm0();
        __syncthreads();

        // ---- fragments from LDS (swizzled b128 reads) + sequenced products ----
        bfrag fa[4], fb[4], f2[4];
#pragma unroll
        for (int mi = 0; mi < 4; ++mi) {
            const int ar = arow + mi * 16 + fr;
            fa[mi] = *(const bfrag*)(Ah + ar * 32 + (fq ^ SW3(ar)) * 8);
        }
#pragma unroll
        for (int ni = 0; ni < 4; ++ni) {
            const int br = brow + ni * 16 + fr;
            fb[ni] = *(const bfrag*)(Bh + br * 32 + (fq ^ SW3(br)) * 8);
        }
        // hh
#pragma unroll
        for (int mi = 0; mi < 4; ++mi)
#pragma unroll
            for (int ni = 0; ni < 4; ++ni)
                acc[mi][ni] = __builtin_amdgcn_mfma_f32_16x16x32_bf16(fa[mi], fb[ni], acc[mi][ni], 0, 0, 0);
        // lh (al x bh)
#pragma unroll
        for (int mi = 0; mi < 4; ++mi) {
            const int ar = arow + mi * 16 + fr;
            f2[mi] = *(const bfrag*)(Al + ar * 32 + (fq ^ SW3(ar)) * 8);
        }
#pragma unroll
        for (int mi = 0; mi < 4; ++mi)
#pragma unroll
            for (int ni = 0; ni < 4; ++ni)
                acc[mi][ni] = __builtin_amdgcn_mfma_f32_16x16x32_bf16(f2[mi], fb[ni], acc[mi][ni], 0, 0, 0);
        // hl (ah x bl) — overwrite fb with Bl
#pragma unroll
        for (int ni = 0; ni < 4; ++ni) {
            const int br = brow + ni * 16 + fr;
            fb[ni] = *(const bfrag*)(Bl + br * 32 + (fq ^ SW3(br)) * 8);
        }
#pragma unroll
        for (int mi = 0; mi < 4; ++mi)
#pragma unroll
            for (int ni = 0; ni < 4; ++ni)
                acc[mi][ni] = __builtin_amdgcn_mfma_f32_16x16x32_bf16(fa[mi], fb[ni], acc[mi][ni], 0, 0, 0);
        // ll (al x bl)
#pragma unroll
        for (int mi = 0; mi < 4; ++mi)
#pragma unroll
            for (int ni = 0; ni < 4; ++ni)
                acc[mi][ni] = __builtin_amdgcn_mfma_f32_16x16x32_bf16(f2[mi], fb[ni], acc[mi][ni], 0, 0, 0);

        __syncthreads();   // all waves done reading before next stage overwrites
    }
    // epilogue: S[row][col] = (qn + kn - 2*dot) * SCALE2
#pragma unroll
    for (int mi = 0; mi < 4; ++mi) {
        float qnr[4];
#pragma unroll
        for (int r = 0; r < 4; ++r) qnr[r] = qn[r0 + arow + mi * 16 + fq * 4 + r];
#pragma unroll
        for (int ni = 0; ni < 4; ++ni) {
            const int col = c0 + brow + ni * 16 + fr;
            const float knc = kn[col];
#pragma unroll
            for (int r = 0; r < 4; ++r) {
                const int row = r0 + arow + mi * 16 + fq * 4 + r;
                S[(size_t)row * NR + col] = (qnr[r] + knc - 2.0f * acc[mi][ni][r]) * SCALE2;
            }
        }
    }
}

// ---------------- MLP logits: relu(A@W1+b1)@W2 + b2 ----------------
__global__ __launch_bounds__(128) void mlp_logits(const float* __restrict__ A,
                                                  const float* __restrict__ W1,
                                                  const float* __restrict__ b1,
                                                  const float* __restrict__ W2,
                                                  const float* __restrict__ b2,
                                                  float* __restrict__ logits) {
    __shared__ float ar[DIM];
    __shared__ float red[2];
    const int t = threadIdx.x;
    const int row = blockIdx.x;
    *(float2*)&ar[t * 2] = *(const float2*)(A + (size_t)row * DIM + t * 2);
    __syncthreads();
    float h = b1[t];
#pragma unroll 8
    for (int kk = 0; kk < DIM; ++kk) h = fmaf(ar[kk], W1[kk * 128 + t], h);
    float val = fmaxf(h, 0.0f) * W2[t];
#pragma unroll
    for (int off = 32; off > 0; off >>= 1) val += __shfl_xor(val, off);
    if ((t & 63) == 0) red[t >> 6] = val;
    __syncthreads();
    if (t == 0) logits[row] = red[0] + red[1] + b2[0];
}

// ---------------- softmax over 8192 logits -> log2(b + 1e-20) ----------------
__global__ __launch_bounds__(1024) void softmax_logb(const float* __restrict__ logits,
                                                     float* __restrict__ logb2) {
    __shared__ float redm[16], reds[16];
    const int t = threadIdx.x;
    float l[8];
    float m = -INFINITY;
#pragma unroll
    for (int i = 0; i < 8; ++i) { l[i] = logits[i * 1024 + t]; m = fmaxf(m, l[i]); }
#pragma unroll
    for (int off = 32; off > 0; off >>= 1) m = fmaxf(m, __shfl_xor(m, off));
    if ((t & 63) == 0) redm[t >> 6] = m;
    __syncthreads();
    if (t < 64) {
        float v = (t < 16) ? redm[t] : -INFINITY;
#pragma unroll
        for (int off = 8; off > 0; off >>= 1) v = fmaxf(v, __shfl_xor(v, off));
        if (t == 0) redm[0] = v;
    }
    __syncthreads();
    m = redm[0];
    float s = 0.0f;
#pragma unroll
    for (int i = 0; i < 8; ++i) s += __expf(l[i] - m);
#pragma unroll
    for (int off = 32; off > 0; off >>= 1) s += __shfl_xor(s, off);
    if ((t & 63) == 0) reds[t >> 6] = s;
    __syncthreads();
    if (t < 64) {
        float v = (t < 16) ? reds[t] : 0.0f;
#pragma unroll
        for (int off = 8; off > 0; off >>= 1) v += __shfl_xor(v, off);
        if (t == 0) reds[0] = v;
    }
    __syncthreads();
    s = reds[0];
    float invs = 1.0f / s;
#pragma unroll
    for (int i = 0; i < 8; ++i)
        logb2[i * 1024 + t] = log2f(__expf(l[i] - m) * invs + 1e-20f);
}

// ---------------- fused iteration: DMA staging + 2 blocks/CU overlap ----------------
// (R0-proven structure: 54 us/iter, VGPR=64, zero scratch.)
__global__ __launch_bounds__(512, 4) void iter_fused(const float* __restrict__ S,
                                                     const float* __restrict__ g,
                                                     const float* __restrict__ logb2,
                                                     float* __restrict__ f,
                                                     float* __restrict__ pm) {
    __shared__ float buf[RSC][NR];      // 64 KB staging (single buffer)
    __shared__ float redm[8], reds[8];
    const int t = threadIdx.x;
    const int wv = t >> 6, lane = t & 63;
    const int chunk = blockIdx.x;
    const int r0 = chunk * CROWS;
    const int rw = wv >> 2;             // row (0..1) within sub-chunk
    const int qt = wv & 3;              // quarter of the row this wave handles
    const int qbase = qt * 2048;
    const int loff = lane * 4;

    // preload this wave's g quarter (constant within one launch): 8 float4
    float4 greg[8];
#pragma unroll
    for (int it = 0; it < 8; ++it)
        greg[it] = *(const float4*)(g + qbase + it * 256 + loff);

    // column accumulators: thread t owns cols {j*2048 + t*4 + c}
    float cm[4][4], cs[4][4];
#pragma unroll
    for (int j = 0; j < 4; ++j)
#pragma unroll
        for (int c = 0; c < 4; ++c) { cm[j][c] = -INFINITY; cs[j][c] = 0.0f; }

    // prologue: DMA sub-chunk 0
    {
        const float* Sr = S + (size_t)(r0 + rw) * NR + qbase;
        float* ld = &buf[rw][qbase];
#pragma unroll
        for (int it = 0; it < 8; ++it)
#if __has_builtin(__builtin_amdgcn_global_load_lds)
            gl2lds16(Sr + it * 256 + loff, ld + it * 256);
#else
            gl2lds16(Sr + it * 256 + loff, ld + it * 256 + loff);
#endif
    }

    for (int sc = 0; sc < NSUB; ++sc) {
        wait_vm0();   // own DMA(sc) (and greg/f stragglers) complete
        // ---- phase 1: row-LSE over this wave's quarter (LDS + g regs) ----
        float m = -INFINITY, s = 0.0f;
#pragma unroll
        for (int it = 0; it < 8; ++it) {
            float4 v = *(const float4*)&buf[rw][qbase + it * 256 + loff];
            float4 gv = greg[it];
            lse_upd4(m, s, v.x + gv.x, v.y + gv.y, v.z + gv.z, v.w + gv.w);
        }
#pragma unroll
        for (int off = 32; off > 0; off >>= 1) {
            float mo = __shfl_xor(m, off);
            float so = __shfl_xor(s, off);
            lse_comb2(m, s, mo, so);
        }
        if (lane == 0) { redm[wv] = m; reds[wv] = s; }
        bar_lgkm();   // barrier A: all DMA(sc) complete block-wide; red visible

        // ---- all threads: combine 4 quarter partials per row -> f0, f1 ----
        float fr[RSC];
#pragma unroll
        for (int r = 0; r < RSC; ++r) {
            float mm = redm[r * 4 + 0], ss = reds[r * 4 + 0];
            lse_comb2(mm, ss, redm[r * 4 + 1], reds[r * 4 + 1]);
            lse_comb2(mm, ss, redm[r * 4 + 2], reds[r * 4 + 2]);
            lse_comb2(mm, ss, redm[r * 4 + 3], reds[r * 4 + 3]);
            fr[r] = logb2[r0 + sc * RSC + r] - (mm + flog2(ss));
        }
        if (t < RSC) f[r0 + sc * RSC + t] = fr[t];

        // ---- phase 2: column partial-LSE over the 2 staged rows (LDS) ----
#pragma unroll
        for (int j = 0; j < 4; ++j) {
            const int c = j * 2048 + t * 4;
            float4 a = *(const float4*)&buf[0][c];
            float4 bb = *(const float4*)&buf[1][c];
            lse_upd2(cm[j][0], cs[j][0], a.x + fr[0], bb.x + fr[1]);
            lse_upd2(cm[j][1], cs[j][1], a.y + fr[0], bb.y + fr[1]);
            lse_upd2(cm[j][2], cs[j][2], a.z + fr[0], bb.z + fr[1]);
            lse_upd2(cm[j][3], cs[j][3], a.w + fr[0], bb.w + fr[1]);
        }
        bar_lgkm();   // barrier B: every wave done reading buf

        // ---- issue DMA for sub-chunk sc+1 (safe: all reads of buf finished) ----
        if (sc + 1 < NSUB) {
            const float* Sn = S + (size_t)(r0 + (sc + 1) * RSC + rw) * NR + qbase;
            float* ld = &buf[rw][qbase];
#pragma unroll
            for (int it = 0; it < 8; ++it)
#if __has_builtin(__builtin_amdgcn_global_load_lds)
                gl2lds16(Sn + it * 256 + loff, ld + it * 256);
#else
                gl2lds16(Sn + it * 256 + loff, ld + it * 256 + loff);
#endif
        }
    }
    // write column partials for this chunk as a single float L = m + log2(s)
#pragma unroll
    for (int j = 0; j < 4; ++j) {
        float4 L;
        L.x = cm[j][0] + flog2(cs[j][0]);
        L.y = cm[j][1] + flog2(cs[j][1]);
        L.z = cm[j][2] + flog2(cs[j][2]);
        L.w = cm[j][3] + flog2(cs[j][3]);
        *(float4*)&pm[(size_t)chunk * NR + j * 2048 + t * 4] = L;
    }
}

// ---------------- combine partials -> g (256 blocks x 1024 threads) ----------------
__global__ __launch_bounds__(1024) void col_combine(const float* __restrict__ pm,
                                                    float* __restrict__ g,
                                                    float log_a2) {
    __shared__ float Lm[32][32], Ls[32][32];
    __shared__ float Lm2[8][32], Ls2[8][32];
    const int t = threadIdx.x;
    const int cl = t & 31;                 // column within block
    const int grp = t >> 5;                // chunk group (0..31), 16 chunks each
    const int col = blockIdx.x * 32 + cl;
    float m = -INFINITY, s = 0.0f;
#pragma unroll
    for (int i = 0; i < 16; i += 4) {
        float l0 = pm[(size_t)(grp * 16 + i + 0) * NR + col];
        float l1 = pm[(size_t)(grp * 16 + i + 1) * NR + col];
        float l2 = pm[(size_t)(grp * 16 + i + 2) * NR + col];
        float l3 = pm[(size_t)(grp * 16 + i + 3) * NR + col];
        lse_upd4(m, s, l0, l1, l2, l3);
    }
    Lm[grp][cl] = m; Ls[grp][cl] = s;
    __syncthreads();
    if (t < 256) {
        const int c = t & 31, q = t >> 5;  // 8 quads of 4 groups
        float mm = Lm[q * 4 + 0][c], ss = Ls[q * 4 + 0][c];
        lse_comb2(mm, ss, Lm[q * 4 + 1][c], Ls[q * 4 + 1][c]);
        lse_comb2(mm, ss, Lm[q * 4 + 2][c], Ls[q * 4 + 2][c]);
        lse_comb2(mm, ss, Lm[q * 4 + 3][c], Ls[q * 4 + 3][c]);
        Lm2[q][c] = mm; Ls2[q][c] = ss;
    }
    __syncthreads();
    if (t < 32) {
        float mm = Lm2[0][t], ss = Ls2[0][t];
#pragma unroll
        for (int q = 1; q < 8; ++q) lse_comb2(mm, ss, Lm2[q][t], Ls2[q][t]);
        g[blockIdx.x * 32 + t] = log_a2 - (mm + flog2(ss));
    }
}

// ---------------- T = exp2(f + S + g), in place; global sum == 1 analytically ------
// note: no __restrict__ on S/out — they alias (in-place)
__global__ __launch_bounds__(256) void write_pass(const float* S,
                                                  const float* __restrict__ f,
                                                  const float* __restrict__ g,
                                                  float* out) {
    const int wv = threadIdx.x >> 6, lane = threadIdx.x & 63;
    const int row = blockIdx.x * 4 + wv;
    const float fi = f[row];
    const float4* Sr = (const float4*)(S + (size_t)row * NR);
    const float4* gr = (const float4*)g;
    float4* Or = (float4*)(out + (size_t)row * NR);
#pragma unroll 4
    for (int it = 0; it < NR / 256; ++it) {
        const int idx = it * 64 + lane;
        float4 sv = Sr[idx];
        float4 gv = gr[idx];
        float4 o;
        o.x = fexp2(fi + sv.x + gv.x);
        o.y = fexp2(fi + sv.y + gv.y);
        o.z = fexp2(fi + sv.z + gv.z);
        o.w = fexp2(fi + sv.w + gv.w);
        Or[idx] = o;
    }
}

extern "C" void kernel_launch(void* const* d_in, const int* in_sizes, int n_in,
                              void* d_out, int out_size, void* d_ws, size_t ws_size,
                              hipStream_t stream) {
    (void)in_sizes; (void)n_in; (void)out_size; (void)ws_size;
    const float* A  = (const float*)d_in[0];
    const float* Tk = (const float*)d_in[1];
    const float* Wq = (const float*)d_in[2];
    const float* bq = (const float*)d_in[3];
    const float* Wk = (const float*)d_in[4];
    const float* bk = (const float*)d_in[5];
    const float* W1 = (const float*)d_in[6];
    const float* b1 = (const float*)d_in[7];
    const float* W2 = (const float*)d_in[8];
    const float* b2 = (const float*)d_in[9];
    float* S  = (float*)d_out;           // 8192x8192 base-2 log_K lives in d_out
    float* ws = (float*)d_ws;
    float* qn     = ws; ws += NR;
    float* kn     = ws; ws += NR;
    float* logb2  = ws; ws += NR;
    float* logits = ws; ws += NR;
    float* f      = ws; ws += NR;
    float* g      = ws; ws += NR;
    float* pm     = ws; ws += (size_t)NBLK * NR;   // 16 MB
    float* q      = ws; ws += (size_t)NR * DIM;    // 8 MB
    float* k      = ws; ws += (size_t)NR * DIM;    // 8 MB
    // bf16 split arrays overlay pm (16.78 MB == 4 x NR*DIM ushorts): they are
    // dead once dist_mfma finishes, before the first iter_fused writes pm.
    ushort_t* qh = (ushort_t*)pm;
    ushort_t* ql = qh + (size_t)NR * DIM;
    ushort_t* kh = ql + (size_t)NR * DIM;
    ushort_t* kl = kh + (size_t)NR * DIM;

    const float log_a2 = -13.0f; // log2(1/8192 + 1e-20)

    init_zero<<<32, 256, 0, stream>>>(g);
    gemm_qk2<<<dim3(128, 4, 2), 256, 0, stream>>>(A, Wq, bq, q, Tk, Wk, bk, k);
    row_norm2<<<2 * NR, 64, 0, stream>>>(q, qn, k, kn);
    split_bf16_2<<<2 * (NR * DIM / 1024), 256, 0, stream>>>(q, qh, ql, k, kh, kl);
    mlp_logits<<<NR, 128, 0, stream>>>(A, W1, b1, W2, b2, logits);
    softmax_logb<<<1, 1024, 0, stream>>>(logits, logb2);
    dist_mfma<<<dim3(64, 64), 256, 0, stream>>>(qh, ql, kh, kl, qn, kn, S);
    for (int it = 0; it < 50; ++it) {
        iter_fused<<<NBLK, 512, 0, stream>>>(S, g, logb2, f, pm);
        col_combine<<<NR / 32, 1024, 0, stream>>>(pm, g, log_a2);
    }
    write_pass<<<NR / 4, 256, 0, stream>>>(S, f, g, S);
}